// Round 13
// baseline (519.969 us; speedup 1.0000x reference)
//
#include <hip/hip_runtime.h>
#include <hip/hip_bf16.h>

#define B_ 8
#define N_ 1024
#define K_ 20
#define BN_ (B_*N_)

#define BN_SCALE 0.9999950000374997f

typedef __attribute__((ext_vector_type(8))) short short8;
typedef __attribute__((ext_vector_type(4))) float f32x4;

__device__ __forceinline__ float US2F(unsigned short u) {
    union { unsigned u; float f; } c; c.u = ((unsigned)u) << 16; return c.f;
}
__device__ __forceinline__ unsigned short F2BF(float f) {   // RNE fp32->bf16
    union { float f; unsigned u; } c; c.f = f;
    unsigned r = c.u + 0x7FFF + ((c.u >> 16) & 1);
    return (unsigned short)(r >> 16);
}

// async global->LDS 16B DMA: LDS dest = wave-uniform base + lane*16 (linear);
// global source is per-lane (pre-swizzled there when a swizzled layout is wanted).
__device__ __forceinline__ void ldsld16(const unsigned short* g, unsigned short* l) {
    __builtin_amdgcn_global_load_lds(
        (const __attribute__((address_space(1))) void*)g,
        (__attribute__((address_space(3))) void*)l, 16, 0, 0);
}

// dtype-detect data: first element of 7 gamma vectors (bf16 gammas ~1.0)
struct DetP { const unsigned short* g[7]; };
__device__ __forceinline__ int det_isbf(const DetP& dp) {
    int cnt = 0;
    #pragma unroll
    for (int i = 0; i < 7; i++) {
        float v = US2F(dp.g[i][0]);
        if (v > 0.5f && v < 1.5f) cnt++;
    }
    return cnt >= 4;
}

// ---------------------------------------------------------------- prep (+ transposes + L1 split)
struct TPar { const void* src; void* dst; int O, I, blk0, mode; };
struct TList { TPar p[44]; };
struct TrP { const void* src; float* dst; int O, I, bx, blk0; };

__global__ __launch_bounds__(256) void k_prep(TList tl, int nent,
                                              TrP q0, TrP q1, TrP q2,
                                              int nbp, int nbtr,
                                              const void* x0, DetP dp,
                                              unsigned short* __restrict__ xa,
                                              unsigned short* __restrict__ xb,
                                              float* __restrict__ xx1) {
    __shared__ int sbf;
    if (threadIdx.x == 0) sbf = det_isbf(dp);
    __syncthreads();
    const int isbf = sbf;
    auto ld0 = [&](int idx) {
        return isbf ? US2F(((const unsigned short*)x0)[idx])
                    : ((const float*)x0)[idx];
    };
    const int bid = blockIdx.x;
    if (bid >= nbp + nbtr) {               // ---- region 3: L1 split + norms
        int blk = bid - nbp - nbtr;
        if (blk >= (BN_ * 32) / 256) {     // norms (32 blocks)
            int i = (blk - (BN_ * 32) / 256) * 256 + threadIdx.x;
            if (i >= BN_) return;
            float s = 0.f;
            #pragma unroll
            for (int c = 0; c < 3; c++) { float v = ld0(i * 3 + c); s += v * v; }
            xx1[i] = s;
            return;
        }
        const int e = blk * 256 + threadIdx.x;   // e < BN_*32
        const int i = e >> 5, p = e & 31;
        unsigned short va = 0, vb = 0;
        if (p < 9) {                        // 3 segs x C=3
            const int seg = p / 3, c = p - seg * 3;
            const float v = ld0(i * 3 + c);
            const unsigned short h = F2BF(v);
            const unsigned short l = F2BF(v - US2F(h));
            va = (seg == 1) ? l : h;        // hi,lo,hi
            vb = (seg < 2) ? h : l;         // hi,hi,lo
        }
        xa[e] = va; xb[e] = vb;
        return;
    }
    if (bid >= nbp) {                      // ---- region 2: transposes
        int blk = bid - nbp;
        TrP p = q0;
        if (blk >= q2.blk0) p = q2; else if (blk >= q1.blk0) p = q1;
        blk -= p.blk0;
        const int tx = threadIdx.x & 31, ty = threadIdx.x >> 5;   // 32 x 8
        const int bi = blk % p.bx, bo = blk / p.bx;
        const int i0 = bi * 32, o0 = bo * 32;
        __shared__ float s[32][33];
        #pragma unroll
        for (int r = 0; r < 4; r++) {
            const int o = o0 + ty + r * 8, i = i0 + tx;
            if (o < p.O && i < p.I) {
                const size_t e = (size_t)o * p.I + i;
                s[ty + r * 8][tx] = isbf ? US2F(((const unsigned short*)p.src)[e])
                                         : ((const float*)p.src)[e];
            }
        }
        __syncthreads();
        #pragma unroll
        for (int r = 0; r < 4; r++) {
            const int i = i0 + ty + r * 8, o = o0 + tx;
            if (i < p.I && o < p.O) p.dst[(size_t)i * p.O + o] = s[tx][ty + r * 8];
        }
        return;
    }
    int blk = bid;                          // ---- region 1: entries
    int wi = 0;
    for (int j = nent - 1; j >= 0; j--) { if (blk >= tl.p[j].blk0) { wi = j; break; } }
    const TPar p = tl.p[wi];
    int e = (blk - p.blk0) * 256 + threadIdx.x;
    int n = p.O * p.I;
    if (e >= n) return;
    if (p.mode == 4) { ((float*)p.dst)[e] = 0.f; return; }
    int o = e / p.I, i = e - o * p.I;
    float v = isbf ? US2F(((const unsigned short*)p.src)[e])
                   : ((const float*)p.src)[e];
    if (p.mode == 0) {
        ((float*)p.dst)[(size_t)i * p.O + o] = v;
    } else if (p.mode == 2) {
        ((unsigned short*)p.dst)[e] = F2BF(v);
    } else {
        const int C = p.I >> 1;
        if (i < C) ((unsigned short*)p.dst)[(size_t)o * C + i] = F2BF(v);
        else       ((unsigned short*)p.dst)[(size_t)(p.O + o) * C + (i - C)] = F2BF(v);
    }
}

// ---------------------------------------------------------------- kNN phase 1 (device body)
// pd[b][i][j] = 2*dot(xa_i, xb_j) - xx_j.  3-seg exact-split over KP=3C.
// Batch-affine: batch = bid&7 -> pd stays in the local XCD L2 for seledge.
template<int KP, int TM, int TN>
__device__ __forceinline__ void pdm_dev(int bid,
                                        const unsigned short* __restrict__ xa,
                                        const unsigned short* __restrict__ xb,
                                        const float* __restrict__ xx,
                                        float* __restrict__ pd) {
    const int b = bid & 7;
    const int tt = bid >> 3;                 // 0..63 tile index within batch
    const int rb = (tt >> 3) * TM, cb = (tt & 7) * TN;
    const unsigned short* Ab = xa + (size_t)b * N_ * KP;
    const unsigned short* Bb = xb + (size_t)b * N_ * KP;
    const float* xxb = xx + (size_t)b * N_;
    const int t = threadIdx.x;
    __shared__ __align__(16) unsigned short As[2][TM * 32];
    __shared__ __align__(16) unsigned short Bs[2][TN * 32];
    const int w = t >> 6, lane = t & 63;
    constexpr int QR = TM / 2, QC = TN / 2;
    constexpr int MR = QR / 16, NR = QC / 16;
    const int wr = (w & 1) * QR, wc = (w >> 1) * QC;
    const int fr = lane & 15, q = lane >> 4;
    f32x4 acc[MR][NR] = {};

    auto STAGE = [&](int buf, int k0) {
        constexpr int AT = TM * 4;
        #pragma unroll
        for (int R = 0; R < (AT + 255) / 256; R++) {
            const int G = t + R * 256;
            if (AT >= (R + 1) * 256 || G < AT) {
                const int m = G >> 2, gs = (G & 3) ^ ((m >> 1) & 3);
                ldsld16(&Ab[(size_t)(rb + m) * KP + k0 + gs * 8], &As[buf][w * 512 + R * 2048]);
            }
        }
        constexpr int BT = TN * 4;
        #pragma unroll
        for (int R = 0; R < (BT + 255) / 256; R++) {
            const int G = t + R * 256;
            if (BT >= (R + 1) * 256 || G < BT) {
                const int n = G >> 2, gs = (G & 3) ^ ((n >> 1) & 3);
                ldsld16(&Bb[(size_t)(cb + n) * KP + k0 + gs * 8], &Bs[buf][w * 512 + R * 2048]);
            }
        }
    };

    constexpr int NT = KP / 32;
    STAGE(0, 0);
    asm volatile("s_waitcnt vmcnt(0)" ::: "memory");
    __builtin_amdgcn_s_barrier();
    int cur = 0;
    for (int ts = 0; ts < NT; ++ts) {
        if (ts + 1 < NT) STAGE(cur ^ 1, (ts + 1) * 32);
        short8 af[MR], bfr[NR];
        #pragma unroll
        for (int mi = 0; mi < MR; mi++) {
            const int r = wr + mi * 16 + fr;
            af[mi] = *reinterpret_cast<const short8*>(&As[cur][r * 32 + ((q ^ ((r >> 1) & 3)) << 3)]);
        }
        #pragma unroll
        for (int ni = 0; ni < NR; ni++) {
            const int r = wc + ni * 16 + fr;
            bfr[ni] = *reinterpret_cast<const short8*>(&Bs[cur][r * 32 + ((q ^ ((r >> 1) & 3)) << 3)]);
        }
        #pragma unroll
        for (int mi = 0; mi < MR; mi++) {
            #pragma unroll
            for (int ni = 0; ni < NR; ni++)
                acc[mi][ni] = __builtin_amdgcn_mfma_f32_16x16x32_bf16(af[mi], bfr[ni], acc[mi][ni], 0, 0, 0);
        }
        asm volatile("s_waitcnt vmcnt(0)" ::: "memory");
        __builtin_amdgcn_s_barrier();
        cur ^= 1;
    }
    float* pdb = pd + (size_t)b * N_ * N_;
    const int cr = (lane >> 4) * 4, cc = lane & 15;
    #pragma unroll
    for (int mi = 0; mi < MR; mi++) {
        #pragma unroll
        for (int ni = 0; ni < NR; ni++) {
            #pragma unroll
            for (int r = 0; r < 4; r++) {
                const int row = rb + wr + mi * 16 + cr + r;
                const int col = cb + wc + ni * 16 + cc;
                pdb[(size_t)row * N_ + col] = 2.f * acc[mi][ni][r] - xxb[col];
            }
        }
    }
}

// ---------------------------------------------------------------- MFMA bf16 GEMM (device body)
template<int KD, int NC, int TM, int TN, bool CATA, bool POOL, int SPLIT>
__device__ __forceinline__ void gemm_dev(int bx, int by,
                                         const unsigned short* __restrict__ A,
                                         const unsigned short* __restrict__ A2,
                                         const unsigned short* __restrict__ A3,
                                         const unsigned short* __restrict__ A4,
                                         const unsigned short* __restrict__ Bw,
                                         const float* __restrict__ bias,
                                         const float* __restrict__ resid,
                                         float* __restrict__ Cout,
                                         float* __restrict__ Cz, int yco,
                                         int scale_cols, float qs,
                                         const float* __restrict__ gamma,
                                         const float* __restrict__ beta,
                                         unsigned short* __restrict__ obf,
                                         unsigned* __restrict__ pmaxu,
                                         float* __restrict__ psum,
                                         unsigned short* __restrict__ sxa,
                                         unsigned short* __restrict__ sxb,
                                         float* __restrict__ xxo) {
    const int t = threadIdx.x;
    const int rb = bx * TM, cb = by * TN;
    const int w = t >> 6, lane = t & 63;
    constexpr int QR = TM / 2, QC = TN / 2;
    constexpr int MR = QR / 16, NR = QC / 16;
    const int wr = (w & 1) * QR, wc = (w >> 1) * QC;
    const int fr = lane & 15, q = lane >> 4, fq = q * 8;
    f32x4 acc[MR][NR] = {};
    if constexpr (KD % 32 == 0) {
        __shared__ __align__(16) unsigned short As[2][TM * 32];
        __shared__ __align__(16) unsigned short Bs[2][TN * 32];
        auto STAGE = [&](int buf, int k0) {
            const unsigned short* Asrc = A; int AC = KD, ac0 = k0;
            if constexpr (CATA) {
                if (k0 >= 256)      { Asrc = A4; AC = 256; ac0 = k0 - 256; }
                else if (k0 >= 128) { Asrc = A3; AC = 128; ac0 = k0 - 128; }
                else if (k0 >= 64)  { Asrc = A2; AC = 64;  ac0 = k0 - 64; }
                else                { Asrc = A;  AC = 64;  ac0 = k0; }
            }
            constexpr int AT = TM * 4;
            #pragma unroll
            for (int R = 0; R < (AT + 255) / 256; R++) {
                const int G = t + R * 256;
                if (AT >= (R + 1) * 256 || G < AT) {
                    const int m = G >> 2, gs = (G & 3) ^ ((m >> 1) & 3);
                    ldsld16(&Asrc[(size_t)(rb + m) * AC + ac0 + gs * 8], &As[buf][w * 512 + R * 2048]);
                }
            }
            constexpr int BT = TN * 4;
            #pragma unroll
            for (int R = 0; R < (BT + 255) / 256; R++) {
                const int G = t + R * 256;
                if (BT >= (R + 1) * 256 || G < BT) {
                    const int n = G >> 2, gs = (G & 3) ^ ((n >> 1) & 3);
                    ldsld16(&Bw[(size_t)(cb + n) * KD + k0 + gs * 8], &Bs[buf][w * 512 + R * 2048]);
                }
            }
        };
        constexpr int NT = KD / 32;
        STAGE(0, 0);
        asm volatile("s_waitcnt vmcnt(0)" ::: "memory");
        __builtin_amdgcn_s_barrier();
        int cur = 0;
        for (int ts = 0; ts < NT; ++ts) {
            if (ts + 1 < NT) STAGE(cur ^ 1, (ts + 1) * 32);
            short8 af[MR], bfr[NR];
            #pragma unroll
            for (int mi = 0; mi < MR; mi++) {
                const int r = wr + mi * 16 + fr;
                af[mi] = *reinterpret_cast<const short8*>(&As[cur][r * 32 + ((q ^ ((r >> 1) & 3)) << 3)]);
            }
            #pragma unroll
            for (int ni = 0; ni < NR; ni++) {
                const int r = wc + ni * 16 + fr;
                bfr[ni] = *reinterpret_cast<const short8*>(&Bs[cur][r * 32 + ((q ^ ((r >> 1) & 3)) << 3)]);
            }
            #pragma unroll
            for (int mi = 0; mi < MR; mi++) {
                #pragma unroll
                for (int ni = 0; ni < NR; ni++)
                    acc[mi][ni] = __builtin_amdgcn_mfma_f32_16x16x32_bf16(af[mi], bfr[ni], acc[mi][ni], 0, 0, 0);
            }
            asm volatile("s_waitcnt vmcnt(0)" ::: "memory");
            __builtin_amdgcn_s_barrier();
            cur ^= 1;
        }
    } else {
        // fallback (KD=3): reg-staged, padded LDS, scalar guarded loads
        __shared__ __align__(16) unsigned short As[TM * 40];
        __shared__ __align__(16) unsigned short Bs[TN * 40];
        for (int k0 = 0; k0 < KD; k0 += 32) {
            __syncthreads();
            #pragma unroll
            for (int u = t; u < TM * 4; u += 256) {
                const int m = u >> 2, c = (u & 3) * 8;
                #pragma unroll
                for (int j = 0; j < 8; j++) {
                    const int kk = k0 + c + j;
                    As[m * 40 + c + j] = (kk < KD) ? A[(size_t)(rb + m) * KD + kk] : (unsigned short)0;
                }
            }
            #pragma unroll
            for (int u = t; u < TN * 4; u += 256) {
                const int n = u >> 2, c = (u & 3) * 8;
                const int gn = cb + n;
                if (gn < NC) {
                    #pragma unroll
                    for (int j = 0; j < 8; j++) {
                        const int kk = k0 + c + j;
                        Bs[n * 40 + c + j] = (kk < KD) ? Bw[(size_t)gn * KD + kk] : (unsigned short)0;
                    }
                } else {
                    short8 z = {};
                    *reinterpret_cast<short8*>(&Bs[n * 40 + c]) = z;
                }
            }
            __syncthreads();
            short8 af[MR], bfr[NR];
            #pragma unroll
            for (int mi = 0; mi < MR; mi++)
                af[mi] = *reinterpret_cast<const short8*>(&As[(wr + mi * 16 + fr) * 40 + fq]);
            #pragma unroll
            for (int ni = 0; ni < NR; ni++)
                bfr[ni] = *reinterpret_cast<const short8*>(&Bs[(wc + ni * 16 + fr) * 40 + fq]);
            #pragma unroll
            for (int mi = 0; mi < MR; mi++) {
                #pragma unroll
                for (int ni = 0; ni < NR; ni++)
                    acc[mi][ni] = __builtin_amdgcn_mfma_f32_16x16x32_bf16(af[mi], bfr[ni], acc[mi][ni], 0, 0, 0);
            }
        }
    }
    const int cr = (lane >> 4) * 4, cc = lane & 15;
    if constexpr (POOL) {
        const int bidx = rb >> 10;
        #pragma unroll
        for (int ni = 0; ni < NR; ni++) {
            const int col = cb + wc + ni * 16 + cc;
            const float gm = gamma[col] * BN_SCALE, bt = beta[col];
            float sm = 0.f, mxv = -3e38f;
            #pragma unroll
            for (int mi = 0; mi < MR; mi++) {
                #pragma unroll
                for (int r = 0; r < 4; r++) {
                    float v = acc[mi][ni][r] * gm + bt;
                    v = v >= 0.f ? v : 0.2f * v;
                    sm += v; mxv = fmaxf(mxv, v);
                }
            }
            sm += __shfl_xor(sm, 16, 64);
            sm += __shfl_xor(sm, 32, 64);
            mxv = fmaxf(mxv, __shfl_xor(mxv, 16, 64));
            mxv = fmaxf(mxv, __shfl_xor(mxv, 32, 64));
            if (lane < 16) {
                atomicAdd(&psum[bidx * 1024 + col], sm);
                unsigned tb = __float_as_uint(mxv);
                tb = (tb & 0x80000000u) ? ~tb : (tb | 0x80000000u);
                atomicMax(&pmaxu[bidx * 1024 + col], tb);
            }
        }
    } else {
        float sx[MR][4] = {};
        #pragma unroll
        for (int mi = 0; mi < MR; mi++) {
            #pragma unroll
            for (int ni = 0; ni < NR; ni++) {
                #pragma unroll
                for (int r = 0; r < 4; r++) {
                    const int row = rb + wr + mi * 16 + cr + r;
                    const int col = cb + wc + ni * 16 + cc;
                    if (col < NC) {
                        float v = acc[mi][ni][r] + (bias ? bias[col] : 0.f);
                        if (col < scale_cols) v *= qs;
                        if (resid) v += resid[(size_t)row * NC + col];
                        if (gamma) {
                            v = v * (gamma[col] * BN_SCALE) + beta[col];
                            v = v >= 0.f ? v : 0.2f * v;
                        }
                        if (yco > 0) {
                            if (col < yco) Cout[(size_t)row * yco + col] = v;
                            else           Cz[(size_t)row * yco + (col - yco)] = v;
                        } else {
                            Cout[(size_t)row * NC + col] = v;
                        }
                        if (obf) obf[(size_t)row * NC + col] = F2BF(v);
                        if constexpr (SPLIT > 0) {
                            constexpr int KP2 = 3 * SPLIT;
                            const unsigned short h = F2BF(v);
                            const unsigned short l = F2BF(v - US2F(h));
                            sxa[(size_t)row * KP2 + 0 * SPLIT + col] = h;
                            sxa[(size_t)row * KP2 + 1 * SPLIT + col] = l;
                            sxa[(size_t)row * KP2 + 2 * SPLIT + col] = h;
                            sxb[(size_t)row * KP2 + 0 * SPLIT + col] = h;
                            sxb[(size_t)row * KP2 + 1 * SPLIT + col] = h;
                            sxb[(size_t)row * KP2 + 2 * SPLIT + col] = l;
                            sx[mi][r] += v * v;
                        }
                    }
                }
            }
        }
        if constexpr (SPLIT > 0) {
            #pragma unroll
            for (int mi = 0; mi < MR; mi++) {
                #pragma unroll
                for (int r = 0; r < 4; r++) {
                    float s = sx[mi][r];
                    s += __shfl_xor(s, 1, 64);
                    s += __shfl_xor(s, 2, 64);
                    s += __shfl_xor(s, 4, 64);
                    s += __shfl_xor(s, 8, 64);
                    if ((lane & 15) == 0)
                        atomicAdd(&xxo[rb + wr + mi * 16 + cr + r], s);
                }
            }
        }
    }
}

// AFF: remap blockIdx.x so row-block batch == XCD (linear id % 8).
template<int KD, int NC, int TM, int TN, bool CATA = false, bool POOL = false, int SPLIT = 0, bool AFF = false>
__global__ __launch_bounds__(256) void k_gemmb(const unsigned short* __restrict__ A,
                                               const unsigned short* __restrict__ A2,
                                               const unsigned short* __restrict__ A3,
                                               const unsigned short* __restrict__ A4,
                                               const unsigned short* __restrict__ Bw,
                                               const float* __restrict__ bias,
                                               const float* __restrict__ resid,
                                               float* __restrict__ Cout,
                                               int scale_cols, float qs,
                                               const float* __restrict__ gamma,
                                               const float* __restrict__ beta,
                                               unsigned short* __restrict__ obf,
                                               unsigned* __restrict__ pmaxu,
                                               float* __restrict__ psum,
                                               unsigned short* __restrict__ sxa,
                                               unsigned short* __restrict__ sxb,
                                               float* __restrict__ xxo) {
    int bx = blockIdx.x;
    if constexpr (AFF) bx = (bx & 7) * (gridDim.x >> 3) + (bx >> 3);
    gemm_dev<KD, NC, TM, TN, CATA, POOL, SPLIT>(bx, blockIdx.y,
        A, A2, A3, A4, Bw, bias, resid, Cout, nullptr, 0, scale_cols, qs, gamma, beta,
        obf, pmaxu, psum, sxa, sxb, xxo);
}

// ---------------------------------------------------------------- combined pdm || yz-GEMM
// Both depend only on the previous layer's outputs: blocks [0,512) = pdm
// (batch-affine), rest = yz edge-feature gemm (batch-affine remap; routes y/z
// cols to the dense arrays the seledge gather reads from the same XCD's L2).
template<int KP, int KDY, int NCY, int TMY, int TNY>
__global__ __launch_bounds__(256) void k_pdmyz(const unsigned short* __restrict__ xa,
                                               const unsigned short* __restrict__ xb,
                                               const float* __restrict__ xx,
                                               float* __restrict__ pd,
                                               const unsigned short* __restrict__ Ay,
                                               const unsigned short* __restrict__ Bwy,
                                               float* __restrict__ Cy,
                                               float* __restrict__ Cz, int yco, int gxy) {
    if ((int)blockIdx.x < 512) { pdm_dev<KP, 128, 128>(blockIdx.x, xa, xb, xx, pd); return; }
    const int g = blockIdx.x - 512;           // 512 ≡ 0 mod 8 -> XCD = g&7
    const int batch = g & 7, rem = g >> 3;
    const int rpb = gxy >> 3;                 // row-blocks per batch
    const int bx = batch * rpb + rem % rpb;
    const int by = rem / rpb;
    gemm_dev<KDY, NCY, TMY, TNY, false, false, 0>(bx, by,
        Ay, nullptr, nullptr, nullptr, Bwy, nullptr, nullptr, Cy, Cz, yco, 0, 1.f,
        nullptr, nullptr, nullptr, nullptr, nullptr, nullptr, nullptr, nullptr);
}

// ---------------------------------------------------------------- fused top-20 selection + EdgeConv gather
// 2048 blocks (32 waves/CU TLP for the serial 20-round chain -- R5/R6 lesson);
// wave w selects row i0+w's top-20 from pd (local XCD L2), indices go to LDS
// (the idx HBM round-trip is eliminated), then the block gathers y-rows for
// its 4 points (batch-affine: same XCD L2 the yz writer filled) and applies
// the max/center/BN/LReLU epilogue.
template<int CO>
__global__ __launch_bounds__(256) void k_seledge(const float* __restrict__ pd,
                                                 const float* __restrict__ y,
                                                 const float* __restrict__ z,
                                                 const float* __restrict__ g,
                                                 const float* __restrict__ bb,
                                                 float* __restrict__ out,
                                                 unsigned short* __restrict__ outb) {
    const int t = threadIdx.x;
    const int w = t >> 6, lane = t & 63;
    const int blk = blockIdx.x;
    const int b = blk & 7;
    const int i0 = (b << 10) + ((blk >> 3) << 2);      // 4 rows per block
    const int bbase = b << 10;
    __shared__ int sidx[4][K_];
    {   // ---- selection (verbatim sel_dev logic, row = i0 + w)
        const int i = i0 + w;
        const float* row = pd + (size_t)b * N_ * N_ + (size_t)(i & 1023) * N_;
        unsigned key[16];
        #pragma unroll
        for (int q = 0; q < 16; q++) {
            const int j = q * 64 + lane;
            unsigned bits = __float_as_uint(row[j]);
            bits = (bits & 0x80000000u) ? ~bits : (bits | 0x80000000u);
            key[q] = (bits & 0xFFFFFC00u) | (unsigned)(N_ - 1 - j);
        }
        int myj = 0;
        for (int kk = 0; kk < K_; kk++) {
            unsigned m = key[0];
            #pragma unroll
            for (int u = 1; u < 16; u++) m = key[u] > m ? key[u] : m;
            #pragma unroll
            for (int s = 1; s < 64; s <<= 1) {
                unsigned o = (unsigned)__shfl_xor((int)m, s, 64);
                m = o > m ? o : m;
            }
            const int j = N_ - 1 - (int)(m & 1023u);
            if (lane == kk) myj = j;
            #pragma unroll
            for (int u = 0; u < 16; u++)
                if (key[u] == m) key[u] = 0u;      // below any plausible real key
        }
        if (lane < K_) sidx[w][lane] = myj;
    }
    __syncthreads();
    // ---- gather + epilogue (old edgemax body, 4 points x CO/4 float4 cols)
    constexpr int TPP = CO / 4;
    if (t < 4 * TPP) {
        const int p = t / TPP;
        const int cw = (t % TPP) * 4;
        const int ig = i0 + p;
        float4 m = {-3e38f, -3e38f, -3e38f, -3e38f};
        #pragma unroll 4
        for (int k = 0; k < K_; k++) {
            const int jg = bbase + sidx[p][k];
            const float4 yv = *reinterpret_cast<const float4*>(&y[(size_t)jg * CO + cw]);
            m.x = fmaxf(m.x, yv.x); m.y = fmaxf(m.y, yv.y);
            m.z = fmaxf(m.z, yv.z); m.w = fmaxf(m.w, yv.w);
        }
        const float4 yi = *reinterpret_cast<const float4*>(&y[(size_t)ig * CO + cw]);
        const float4 zi = *reinterpret_cast<const float4*>(&z[(size_t)ig * CO + cw]);
        const float4 gv = *reinterpret_cast<const float4*>(&g[cw]);
        const float4 bv = *reinterpret_cast<const float4*>(&bb[cw]);
        float vals[4] = {m.x - yi.x + zi.x, m.y - yi.y + zi.y,
                         m.z - yi.z + zi.z, m.w - yi.w + zi.w};
        float gs[4] = {gv.x, gv.y, gv.z, gv.w};
        float bs[4] = {bv.x, bv.y, bv.z, bv.w};
        float4 o;
        float* op = &o.x;
        #pragma unroll
        for (int j = 0; j < 4; j++) {
            float h = vals[j] * (gs[j] * BN_SCALE) + bs[j];
            op[j] = h >= 0.f ? h : 0.2f * h;
        }
        *reinterpret_cast<float4*>(&out[(size_t)ig * CO + cw]) = o;
        #pragma unroll
        for (int j = 0; j < 4; j++) outb[(size_t)ig * CO + cw + j] = F2BF(op[j]);
    }
}

// ---------------------------------------------------------------- fused attention + out-proj (layers 1-3)
template<int E, int SPLIT>
__global__ __launch_bounds__(256) void k_attnout(const float* __restrict__ qkv,
                                                 const unsigned short* __restrict__ wo,
                                                 const float* __restrict__ bo,
                                                 float* __restrict__ x,
                                                 unsigned short* __restrict__ xob,
                                                 unsigned short* __restrict__ sxa,
                                                 unsigned short* __restrict__ sxb,
                                                 float* __restrict__ xxo) {
    constexpr int H = 4, D = E / H, L = 8;
    const int n = blockIdx.x;
    const int t = threadIdx.x;
    const int h = t >> 6, lane = t & 63;
    __shared__ float sq[L][3 * E];
    __shared__ float so[L][E];
    __shared__ unsigned short swo[E][E + 8];
    __shared__ float sxx[L];
    for (int u = t; u < L * 3 * E; u += 256) {
        int l = u / (3 * E), r = u - l * (3 * E);
        sq[l][r] = qkv[(size_t)(l * N_ + n) * (3 * E) + r];
    }
    for (int u = t; u < E * E; u += 256) swo[u / E][u % E] = wo[u];
    if (t < L) sxx[t] = 0.f;
    __syncthreads();
    const int l = lane >> 3, m = lane & 7;
    float s = 0.f;
    #pragma unroll 8
    for (int dd = 0; dd < D; dd++)
        s += sq[l][h * D + dd] * sq[m][E + h * D + dd];
    float mx = s;
    #pragma unroll
    for (int st = 1; st < 8; st <<= 1) mx = fmaxf(mx, __shfl_xor(mx, st, 64));
    float e = expf(s - mx);
    float sum = e;
    #pragma unroll
    for (int st = 1; st < 8; st <<= 1) sum += __shfl_xor(sum, st, 64);
    const float p = e / sum;
    float pm[8];
    #pragma unroll
    for (int mm = 0; mm < 8; mm++) pm[mm] = __shfl(p, (lane & 56) | mm, 64);
    #pragma unroll
    for (int j = 0; j < D / 8; j++) {
        const int dd = m + 8 * j;
        float a = 0.f;
        #pragma unroll
        for (int mm = 0; mm < 8; mm++) a += pm[mm] * sq[mm][2 * E + h * D + dd];
        so[l][h * D + dd] = a;
    }
    __syncthreads();
    for (int u = t; u < L * E; u += 256)
        so[u / E][u % E] = US2F(F2BF(so[u / E][u % E]));
    __syncthreads();
    constexpr int PT = (L * E) / 256;
    #pragma unroll
    for (int it = 0; it < PT; it++) {
        const int item = t + it * 256;
        const int ll = item / E, ee = item % E;
        float acc = 0.f;
        #pragma unroll 16
        for (int c = 0; c < E; c++)
            acc += so[ll][c] * US2F(swo[ee][c]);
        const int row = ll * N_ + n;
        const float v = acc + bo[ee] + x[(size_t)row * E + ee];
        x[(size_t)row * E + ee] = v;
        xob[(size_t)row * E + ee] = F2BF(v);
        if constexpr (SPLIT > 0) {
            constexpr int KP2 = 3 * SPLIT;
            const unsigned short hh = F2BF(v);
            const unsigned short lo = F2BF(v - US2F(hh));
            sxa[(size_t)row * KP2 + 0 * SPLIT + ee] = hh;
            sxa[(size_t)row * KP2 + 1 * SPLIT + ee] = lo;
            sxa[(size_t)row * KP2 + 2 * SPLIT + ee] = hh;
            sxb[(size_t)row * KP2 + 0 * SPLIT + ee] = hh;
            sxb[(size_t)row * KP2 + 1 * SPLIT + ee] = hh;
            sxb[(size_t)row * KP2 + 2 * SPLIT + ee] = lo;
            float vs = v * v;
            #pragma unroll
            for (int st = 1; st < 64; st <<= 1) vs += __shfl_xor(vs, st, 64);
            if (lane == 0) atomicAdd(&sxx[ll], vs);
        }
    }
    if constexpr (SPLIT > 0) {
        __syncthreads();
        if (t < L) xxo[t * N_ + n] = sxx[t];
    }
}

// ---------------------------------------------------------------- fused attention + out-proj (layer 4, E=256)
// wo (128 KB bf16) can't fit LDS whole: chunk-stage 32 columns at a time as
// fp32 ([256][33] = 33.8 KB, padded -> 2-way), accumulating the 8 per-thread
// dots across 8 chunk passes.  Same bf16 pre-quantization of so as the old
// MFMA out-proj path; epilogue = bias + residual (SPLIT=0, last layer).
__global__ __launch_bounds__(256) void k_attnout4(const float* __restrict__ qkv,
                                                  const unsigned short* __restrict__ wo,
                                                  const float* __restrict__ bo,
                                                  float* __restrict__ x,
                                                  unsigned short* __restrict__ xob) {
    constexpr int E = 256, H = 4, D = E / H, L = 8;
    const int n = blockIdx.x;
    const int t = threadIdx.x;
    const int h = t >> 6, lane = t & 63;
    __shared__ float sq[L][3 * E];          // 24 KB
    __shared__ float so[L][E];              // 8 KB
    __shared__ float swoc[E][33];           // 33.8 KB (32-col chunk, padded)
    for (int u = t; u < L * 3 * E; u += 256) {
        int l = u / (3 * E), r = u - l * (3 * E);
        sq[l][r] = qkv[(size_t)(l * N_ + n) * (3 * E) + r];
    }
    __syncthreads();
    const int l = lane >> 3, m = lane & 7;
    float s = 0.f;
    #pragma unroll 8
    for (int dd = 0; dd < D; dd++)
        s += sq[l][h * D + dd] * sq[m][E + h * D + dd];
    float mx = s;
    #pragma unroll
    for (int st = 1; st < 8; st <<= 1) mx = fmaxf(mx, __shfl_xor(mx, st, 64));
    float e = expf(s - mx);
    float sum = e;
    #pragma unroll
    for (int st = 1; st < 8; st <<= 1) sum += __shfl_xor(sum, st, 64);
    const float p = e / sum;
    float pm[8];
    #pragma unroll
    for (int mm = 0; mm < 8; mm++) pm[mm] = __shfl(p, (lane & 56) | mm, 64);
    #pragma unroll
    for (int j = 0; j < D / 8; j++) {
        const int dd = m + 8 * j;
        float a = 0.f;
        #pragma unroll
        for (int mm = 0; mm < 8; mm++) a += pm[mm] * sq[mm][2 * E + h * D + dd];
        so[l][h * D + dd] = a;
    }
    __syncthreads();
    for (int u = t; u < L * E; u += 256)
        so[u / E][u % E] = US2F(F2BF(so[u / E][u % E]));
    constexpr int PT = (L * E) / 256;       // 8 items/thread
    float acc[PT] = {};
    for (int ch = 0; ch < 8; ch++) {        // 8 chunks x 32 cols
        __syncthreads();
        for (int u = t; u < E * 32; u += 256) {
            const int ee = u >> 5, cc = u & 31;
            swoc[ee][cc] = US2F(wo[ee * E + ch * 32 + cc]);
        }
        __syncthreads();
        #pragma unroll
        for (int it = 0; it < PT; it++) {
            const int item = t + it * 256;
            const int ll = item / E, ee = item % E;
            float a = acc[it];
            #pragma unroll
            for (int cc = 0; cc < 32; cc++)
                a += so[ll][ch * 32 + cc] * swoc[ee][cc];
            acc[it] = a;
        }
    }
    #pragma unroll
    for (int it = 0; it < PT; it++) {
        const int item = t + it * 256;
        const int ll = item / E, ee = item % E;
        const int row = ll * N_ + n;
        const float v = acc[it] + bo[ee] + x[(size_t)row * E + ee];
        x[(size_t)row * E + ee] = v;
        xob[(size_t)row * E + ee] = F2BF(v);
    }
}

// ---------------------------------------------------------------- FC head
__global__ __launch_bounds__(256) void k_fc1(const unsigned* __restrict__ pmaxu,
                                             const float* __restrict__ psum,
                                             const float* __restrict__ l1wT,
                                             const float* __restrict__ g6, const float* __restrict__ b6,
                                             float* __restrict__ f1) {
    int oc = blockIdx.x, b = blockIdx.y, t = threadIdx.x;
    __shared__ float fin[2048];
    __shared__ float ps[4][64];
    for (int u = t; u < 2048; u += 256) {
        float v;
        if (u < 1024) {
            unsigned tb = pmaxu[b * 1024 + u];
            unsigned bits = (tb & 0x80000000u) ? (tb & 0x7FFFFFFFu) : ~tb;
            v = __uint_as_float(bits);
        } else {
            v = psum[b * 1024 + (u - 1024)] * (1.f / 1024.f);
        }
        fin[u] = v;
    }
    __syncthreads();
    int ol = t & 63, kc = t >> 6;
    int o = oc * 64 + ol;
    float acc = 0.f;
    for (int c = kc * 512; c < kc * 512 + 512; c++) acc += fin[c] * l1wT[(size_t)c * 512 + o];
    ps[kc][ol] = acc;
    __syncthreads();
    if (t < 64) {
        int oo = oc * 64 + t;
        float a = ps[0][t] + ps[1][t] + ps[2][t] + ps[3][t];
        float h = a * (g6[oo] * BN_SCALE) + b6[oo];
        f1[b * 512 + oo] = h >= 0.f ? h : 0.2f * h;
    }
}

__global__ __launch_bounds__(256) void k_fc23(const float* __restrict__ f1, const float* __restrict__ l2wT,
                                              const float* __restrict__ l2b,
                                              const float* __restrict__ g7, const float* __restrict__ b7,
                                              const float* __restrict__ l3wT, const float* __restrict__ l3b,
                                              void* __restrict__ out, DetP dp) {
    int b = blockIdx.x, t = threadIdx.x;
    __shared__ float fin[512];
    __shared__ float f2s[256];
    __shared__ int sbf;
    if (t == 0) sbf = det_isbf(dp);
    for (int u = t; u < 512; u += 256) fin[u] = f1[b * 512 + u];
    __syncthreads();
    {
        float acc = 0.f;
        for (int c = 0; c < 512; c++) acc += fin[c] * l2wT[(size_t)c * 256 + t];
        acc += l2b[t];
        float h = acc * (g7[t] * BN_SCALE) + b7[t];
        f2s[t] = h >= 0.f ? h : 0.2f * h;
    }
    __syncthreads();
    if (t < 40) {
        float acc = 0.f;
        for (int c = 0; c < 256; c++) acc += f2s[c] * l3wT[(size_t)c * 40 + t];
        acc += l3b[t];
        if (sbf) ((__hip_bfloat16*)out)[b * 40 + t] = __float2bfloat16(acc);
        else     ((float*)out)[b * 40 + t] = acc;
    }
}

// ================================================================ host
extern "C" void kernel_launch(void* const* d_in, const int* in_sizes, int n_in,
                              void* d_out, int out_size, void* d_ws, size_t ws_size,
                              hipStream_t stream) {
    auto us = [&](int i) { return (const unsigned short*)d_in[i]; };

    float* ws = (float*)d_ws;
    size_t off = 0;
    auto A = [&](size_t n) { float* p = ws + off; off += (n + 3) & ~(size_t)3; return p; };
    auto AU = [&](size_t n) { return (unsigned short*)A((n + 1) / 2); };
    float* x1   = A((size_t)BN_ * 64);
    float* x2   = A((size_t)BN_ * 64);
    float* x3   = A((size_t)BN_ * 128);
    float* x4   = A((size_t)BN_ * 256);
    float* pd   = A((size_t)BN_ * 1024);   // pd scratch
    float* f1   = A(8 * 512);
    float* xx   = A(4 * BN_);              // per-layer row norms
    float* qkvw = A((size_t)BN_ * 768);    // qkv / y,z scratch
    // dedicated kNN split buffers (k_attnout reads qkvw while writing these)
    unsigned short* xa = AU((size_t)BN_ * 384);
    unsigned short* xb = AU((size_t)BN_ * 384);
    // bf16 activation copies
    unsigned short* xf0b = AU((size_t)BN_ * 3);
    unsigned short* x1b  = AU((size_t)BN_ * 64);
    unsigned short* x2b  = AU((size_t)BN_ * 64);
    unsigned short* x3b  = AU((size_t)BN_ * 128);
    unsigned short* x4b  = AU((size_t)BN_ * 256);
    // pooled reductions (conv5 fused epilogue) -- contiguous, zeroed by k_prep
    unsigned* pmaxu = (unsigned*)A(8 * 1024);
    float*    psum  = A(8 * 1024);
    // bf16 weights (n,k) layouts
    unsigned short* w1yzb = AU(128 * 3);
    unsigned short* w2yzb = AU(128 * 64);
    unsigned short* w3yzb = AU(256 * 64);
    unsigned short* w4yzb = AU(512 * 128);
    unsigned short* a1wib = AU(192 * 64);  unsigned short* a1wob = AU(64 * 64);
    unsigned short* a2wib = AU(192 * 64);  unsigned short* a2wob = AU(64 * 64);
    unsigned short* a3wib = AU(384 * 128); unsigned short* a3wob = AU(128 * 128);
    unsigned short* a4wib = AU(768 * 256); unsigned short* a4wob = AU(256 * 256);
    unsigned short* w5b   = AU(1024 * 512);
    // fp32 fc weights (transposed)
    float* l1wT  = A(2048 * 512);
    float* l2wT  = A(512 * 256);
    float* l3wT  = A(256 * 40);
    // converted vectors (fp32)
    float* g1f = A(64);   float* b1f = A(64);
    float* g2f = A(64);   float* b2f = A(64);
    float* g3f = A(128);  float* b3f = A(128);
    float* g4f = A(256);  float* b4f = A(256);
    float* bi1 = A(192);  float* bo1 = A(64);
    float* bi2 = A(192);  float* bo2 = A(64);
    float* bi3 = A(384);  float* bo3 = A(128);
    float* bi4 = A(768);  float* bo4 = A(256);
    float* g5f = A(1024); float* b5f = A(1024);
    float* g6f = A(512);  float* b6f = A(512);
    float* l2bf = A(256);
    float* g7f = A(256);  float* b7f = A(256);
    float* l3bf = A(40);

    float* xx1 = xx;              float* xx2 = xx + BN_;
    float* xx3 = xx + 2 * BN_;    float* xx4 = xx + 3 * BN_;

    // y/z edge-feature arrays alias qkvw (qkv gemm later overwrites)
    float* yy = qkvw;
    float* zz = qkvw + (size_t)BN_ * 256;

    DetP dp{{us(2), us(5), us(8), us(11), us(30), us(33), us(37)}};

    TList tl; int nb = 0; int k = 0;
    auto add = [&](int i, void* dst, int O, int I, int mode) {
        tl.p[k].src = d_in[i]; tl.p[k].dst = dst; tl.p[k].O = O; tl.p[k].I = I;
        tl.p[k].blk0 = nb; tl.p[k].mode = mode;
        nb += (O * I + 255) / 256; k++;
    };
    add(0,  xf0b,  BN_ * 3, 1, 2);
    add(0,  pmaxu, 16384, 1, 4);      // zero pmaxu+psum (contiguous)
    add(1,  w1yzb, 64, 6, 3);
    add(4,  w2yzb, 64, 128, 3);
    add(7,  w3yzb, 128, 128, 3);
    add(10, w4yzb, 256, 256, 3);
    add(13, a1wib, 192, 64, 2);
    add(15, a1wob, 64, 64, 2);
    add(17, a2wib, 192, 64, 2);
    add(19, a2wob, 64, 64, 2);
    add(21, a3wib, 384, 128, 2);
    add(23, a3wob, 128, 128, 2);
    add(25, a4wib, 768, 256, 2);
    add(27, a4wob, 256, 256, 2);
    add(29, w5b,   1024, 512, 2);
    add(2,  g1f, 64, 1, 0);   add(3,  b1f, 64, 1, 0);
    add(5,  g2f, 64, 1, 0);   add(6,  b2f, 64, 1, 0);
    add(8,  g3f, 128, 1, 0);  add(9,  b3f, 128, 1, 0);
    add(11, g4f, 256, 1, 0);  add(12, b4f, 256, 1, 0);
    add(14, bi1, 192, 1, 0);  add(16, bo1, 64, 1, 0);
    add(18, bi2, 192, 1, 0);  add(20, bo2, 64, 1, 0);
    add(22, bi3, 384, 1, 0);  add(24, bo3, 128, 1, 0);
    add(26, bi4, 768, 1, 0);  add(28, bo4, 256, 1, 0);
    add(30, g5f, 1024, 1, 0); add(31, b5f, 1024, 1, 0);
    add(33, g6f, 512, 1, 0);  add(34, b6f, 512, 1, 0);
    add(36, l2bf, 256, 1, 0);
    add(37, g7f, 256, 1, 0);  add(38, b7f, 256, 1, 0);
    add(40, l3bf, 40, 1, 0);

    // FC-weight transposes + layer-1 split/norms fused into k_prep tail blocks
    TrP tp1{d_in[32], l1wT, 512, 2048, 2048 / 32, 0};
    TrP tp2{d_in[35], l2wT, 256, 512,  512 / 32,  (2048 / 32) * (512 / 32)};
    TrP tp3{d_in[39], l3wT, 40,  256,  256 / 32,  tp2.blk0 + (512 / 32) * (256 / 32)};
    const int trblocks = tp3.blk0 + (256 / 32) * ((40 + 31) / 32);
    const int splblocks = (BN_ * 32) / 256 + 32;   // split + norms
    k_prep<<<nb + trblocks + splblocks, 256, 0, stream>>>(
        tl, k, tp1, tp2, tp3, nb, trblocks, d_in[0], dp, xa, xb, xx1);

    const unsigned short* N0 = nullptr;
    unsigned short* U0 = nullptr;
    unsigned* NU = nullptr; float* NF = nullptr;

    // layer 1  (C=3 -> 64)
    k_pdmyz<32, 3, 128, 64, 64><<<512 + 256, 256, 0, stream>>>(xa, xb, xx1, pd, xf0b, w1yzb, yy, zz, 64, 128);
    k_seledge<64><<<2048, 256, 0, stream>>>(pd, yy, zz, g1f, b1f, x1, x1b);
    k_gemmb<64, 192, 64, 64, false, false, 0, true><<<dim3(128, 3), 256, 0, stream>>>(x1b, N0, N0, N0, a1wib, bi1, nullptr, qkvw, 64, 0.25f, nullptr, nullptr, nullptr, NU, NF, U0, U0, NF);
    k_attnout<64, 64><<<N_, 256, 0, stream>>>(qkvw, a1wob, bo1, x1, x1b, xa, xb, xx2);

    // layer 2  (C=64 -> 64, KP=192)
    k_pdmyz<192, 64, 128, 64, 64><<<512 + 256, 256, 0, stream>>>(xa, xb, xx2, pd, x1b, w2yzb, yy, zz, 64, 128);
    k_seledge<64><<<2048, 256, 0, stream>>>(pd, yy, zz, g2f, b2f, x2, x2b);
    k_gemmb<64, 192, 64, 64, false, false, 0, true><<<dim3(128, 3), 256, 0, stream>>>(x2b, N0, N0, N0, a2wib, bi2, nullptr, qkvw, 64, 0.25f, nullptr, nullptr, nullptr, NU, NF, U0, U0, NF);
    k_attnout<64, 64><<<N_, 256, 0, stream>>>(qkvw, a2wob, bo2, x2, x2b, xa, xb, xx3);

    // layer 3  (C=64 -> 128, KP=192)
    k_pdmyz<192, 64, 256, 64, 64><<<512 + 512, 256, 0, stream>>>(xa, xb, xx3, pd, x2b, w3yzb, yy, zz, 128, 128);
    k_seledge<128><<<2048, 256, 0, stream>>>(pd, yy, zz, g3f, b3f, x3, x3b);
    k_gemmb<128, 384, 64, 128, false, false, 0, true><<<dim3(128, 3), 256, 0, stream>>>(x3b, N0, N0, N0, a3wib, bi3, nullptr, qkvw, 128, 0.17677669529663687f, nullptr, nullptr, nullptr, NU, NF, U0, U0, NF);
    k_attnout<128, 128><<<N_, 256, 0, stream>>>(qkvw, a3wob, bo3, x3, x3b, xa, xb, xx4);

    // layer 4  (C=128 -> 256, KP=384)
    k_pdmyz<384, 128, 512, 128, 128><<<512 + 256, 256, 0, stream>>>(xa, xb, xx4, pd, x3b, w4yzb, yy, zz, 256, 64);
    k_seledge<256><<<2048, 256, 0, stream>>>(pd, yy, zz, g4f, b4f, x4, x4b);
    k_gemmb<256, 768, 64, 128, false, false, 0, true><<<dim3(128, 6), 256, 0, stream>>>(x4b, N0, N0, N0, a4wib, bi4, nullptr, qkvw, 256, 0.125f, nullptr, nullptr, nullptr, NU, NF, U0, U0, NF);
    k_attnout4<<<N_, 256, 0, stream>>>(qkvw, a4wob, bo4, x4, x4b);

    // head: conv5 with fused concat-A and fused pooling epilogue (batch-affine)
    k_gemmb<512, 1024, 128, 128, true, true, 0, true><<<dim3(64, 8), 256, 0, stream>>>(
        x1b, x2b, x3b, x4b, w5b, nullptr, nullptr, nullptr, 0, 1.f, g5f, b5f, nullptr, pmaxu, psum, U0, U0, NF);
    k_fc1<<<dim3(8, 8), 256, 0, stream>>>(pmaxu, psum, l1wT, g6f, b6f, f1);
    k_fc23<<<8, 256, 0, stream>>>(f1, l2wT, l2bf, g7f, b7f, l3wT, l3bf, d_out, dp);
}

// Round 14
// 475.999 us; speedup vs baseline: 1.0924x; 1.0924x over previous
//
#include <hip/hip_runtime.h>
#include <hip/hip_bf16.h>

#define B_ 8
#define N_ 1024
#define K_ 20
#define BN_ (B_*N_)

#define BN_SCALE 0.9999950000374997f

typedef __attribute__((ext_vector_type(8))) short short8;
typedef __attribute__((ext_vector_type(4))) float f32x4;

__device__ __forceinline__ float US2F(unsigned short u) {
    union { unsigned u; float f; } c; c.u = ((unsigned)u) << 16; return c.f;
}
__device__ __forceinline__ unsigned short F2BF(float f) {   // RNE fp32->bf16
    union { float f; unsigned u; } c; c.f = f;
    unsigned r = c.u + 0x7FFF + ((c.u >> 16) & 1);
    return (unsigned short)(r >> 16);
}

// async global->LDS 16B DMA: LDS dest = wave-uniform base + lane*16 (linear);
// global source is per-lane (pre-swizzled there when a swizzled layout is wanted).
__device__ __forceinline__ void ldsld16(const unsigned short* g, unsigned short* l) {
    __builtin_amdgcn_global_load_lds(
        (const __attribute__((address_space(1))) void*)g,
        (__attribute__((address_space(3))) void*)l, 16, 0, 0);
}

// dtype-detect data: first element of 7 gamma vectors (bf16 gammas ~1.0)
struct DetP { const unsigned short* g[7]; };
__device__ __forceinline__ int det_isbf(const DetP& dp) {
    int cnt = 0;
    #pragma unroll
    for (int i = 0; i < 7; i++) {
        float v = US2F(dp.g[i][0]);
        if (v > 0.5f && v < 1.5f) cnt++;
    }
    return cnt >= 4;
}

// ---------------------------------------------------------------- prep (+ transposes + L1 split)
struct TPar { const void* src; void* dst; int O, I, blk0, mode; };
struct TList { TPar p[44]; };
struct TrP { const void* src; float* dst; int O, I, bx, blk0; };

__global__ __launch_bounds__(256) void k_prep(TList tl, int nent,
                                              TrP q0, TrP q1, TrP q2,
                                              int nbp, int nbtr,
                                              const void* x0, DetP dp,
                                              unsigned short* __restrict__ xa,
                                              unsigned short* __restrict__ xb,
                                              float* __restrict__ xx1) {
    __shared__ int sbf;
    if (threadIdx.x == 0) sbf = det_isbf(dp);
    __syncthreads();
    const int isbf = sbf;
    auto ld0 = [&](int idx) {
        return isbf ? US2F(((const unsigned short*)x0)[idx])
                    : ((const float*)x0)[idx];
    };
    const int bid = blockIdx.x;
    if (bid >= nbp + nbtr) {               // ---- region 3: L1 split + norms
        int blk = bid - nbp - nbtr;
        if (blk >= (BN_ * 32) / 256) {     // norms (32 blocks)
            int i = (blk - (BN_ * 32) / 256) * 256 + threadIdx.x;
            if (i >= BN_) return;
            float s = 0.f;
            #pragma unroll
            for (int c = 0; c < 3; c++) { float v = ld0(i * 3 + c); s += v * v; }
            xx1[i] = s;
            return;
        }
        const int e = blk * 256 + threadIdx.x;   // e < BN_*32
        const int i = e >> 5, p = e & 31;
        unsigned short va = 0, vb = 0;
        if (p < 9) {                        // 3 segs x C=3
            const int seg = p / 3, c = p - seg * 3;
            const float v = ld0(i * 3 + c);
            const unsigned short h = F2BF(v);
            const unsigned short l = F2BF(v - US2F(h));
            va = (seg == 1) ? l : h;        // hi,lo,hi
            vb = (seg < 2) ? h : l;         // hi,hi,lo
        }
        xa[e] = va; xb[e] = vb;
        return;
    }
    if (bid >= nbp) {                      // ---- region 2: transposes
        int blk = bid - nbp;
        TrP p = q0;
        if (blk >= q2.blk0) p = q2; else if (blk >= q1.blk0) p = q1;
        blk -= p.blk0;
        const int tx = threadIdx.x & 31, ty = threadIdx.x >> 5;   // 32 x 8
        const int bi = blk % p.bx, bo = blk / p.bx;
        const int i0 = bi * 32, o0 = bo * 32;
        __shared__ float s[32][33];
        #pragma unroll
        for (int r = 0; r < 4; r++) {
            const int o = o0 + ty + r * 8, i = i0 + tx;
            if (o < p.O && i < p.I) {
                const size_t e = (size_t)o * p.I + i;
                s[ty + r * 8][tx] = isbf ? US2F(((const unsigned short*)p.src)[e])
                                         : ((const float*)p.src)[e];
            }
        }
        __syncthreads();
        #pragma unroll
        for (int r = 0; r < 4; r++) {
            const int i = i0 + ty + r * 8, o = o0 + tx;
            if (i < p.I && o < p.O) p.dst[(size_t)i * p.O + o] = s[tx][ty + r * 8];
        }
        return;
    }
    int blk = bid;                          // ---- region 1: entries
    int wi = 0;
    for (int j = nent - 1; j >= 0; j--) { if (blk >= tl.p[j].blk0) { wi = j; break; } }
    const TPar p = tl.p[wi];
    int e = (blk - p.blk0) * 256 + threadIdx.x;
    int n = p.O * p.I;
    if (e >= n) return;
    if (p.mode == 4) { ((float*)p.dst)[e] = 0.f; return; }
    int o = e / p.I, i = e - o * p.I;
    float v = isbf ? US2F(((const unsigned short*)p.src)[e])
                   : ((const float*)p.src)[e];
    if (p.mode == 0) {
        ((float*)p.dst)[(size_t)i * p.O + o] = v;
    } else if (p.mode == 2) {
        ((unsigned short*)p.dst)[e] = F2BF(v);
    } else {
        const int C = p.I >> 1;
        if (i < C) ((unsigned short*)p.dst)[(size_t)o * C + i] = F2BF(v);
        else       ((unsigned short*)p.dst)[(size_t)(p.O + o) * C + (i - C)] = F2BF(v);
    }
}

// ---------------------------------------------------------------- kNN phase 1 (device body)
// pd[b][i][j] = 2*dot(xa_i, xb_j) - xx_j.  3-seg exact-split over KP=3C.
// Batch-affine: batch = bid&7 -> pd stays in the local XCD L2 for seledge.
template<int KP, int TM, int TN>
__device__ __forceinline__ void pdm_dev(int bid,
                                        const unsigned short* __restrict__ xa,
                                        const unsigned short* __restrict__ xb,
                                        const float* __restrict__ xx,
                                        float* __restrict__ pd) {
    const int b = bid & 7;
    const int tt = bid >> 3;                 // 0..63 tile index within batch
    const int rb = (tt >> 3) * TM, cb = (tt & 7) * TN;
    const unsigned short* Ab = xa + (size_t)b * N_ * KP;
    const unsigned short* Bb = xb + (size_t)b * N_ * KP;
    const float* xxb = xx + (size_t)b * N_;
    const int t = threadIdx.x;
    __shared__ __align__(16) unsigned short As[2][TM * 32];
    __shared__ __align__(16) unsigned short Bs[2][TN * 32];
    const int w = t >> 6, lane = t & 63;
    constexpr int QR = TM / 2, QC = TN / 2;
    constexpr int MR = QR / 16, NR = QC / 16;
    const int wr = (w & 1) * QR, wc = (w >> 1) * QC;
    const int fr = lane & 15, q = lane >> 4;
    f32x4 acc[MR][NR] = {};

    auto STAGE = [&](int buf, int k0) {
        constexpr int AT = TM * 4;
        #pragma unroll
        for (int R = 0; R < (AT + 255) / 256; R++) {
            const int G = t + R * 256;
            if (AT >= (R + 1) * 256 || G < AT) {
                const int m = G >> 2, gs = (G & 3) ^ ((m >> 1) & 3);
                ldsld16(&Ab[(size_t)(rb + m) * KP + k0 + gs * 8], &As[buf][w * 512 + R * 2048]);
            }
        }
        constexpr int BT = TN * 4;
        #pragma unroll
        for (int R = 0; R < (BT + 255) / 256; R++) {
            const int G = t + R * 256;
            if (BT >= (R + 1) * 256 || G < BT) {
                const int n = G >> 2, gs = (G & 3) ^ ((n >> 1) & 3);
                ldsld16(&Bb[(size_t)(cb + n) * KP + k0 + gs * 8], &Bs[buf][w * 512 + R * 2048]);
            }
        }
    };

    constexpr int NT = KP / 32;
    STAGE(0, 0);
    asm volatile("s_waitcnt vmcnt(0)" ::: "memory");
    __builtin_amdgcn_s_barrier();
    int cur = 0;
    for (int ts = 0; ts < NT; ++ts) {
        if (ts + 1 < NT) STAGE(cur ^ 1, (ts + 1) * 32);
        short8 af[MR], bfr[NR];
        #pragma unroll
        for (int mi = 0; mi < MR; mi++) {
            const int r = wr + mi * 16 + fr;
            af[mi] = *reinterpret_cast<const short8*>(&As[cur][r * 32 + ((q ^ ((r >> 1) & 3)) << 3)]);
        }
        #pragma unroll
        for (int ni = 0; ni < NR; ni++) {
            const int r = wc + ni * 16 + fr;
            bfr[ni] = *reinterpret_cast<const short8*>(&Bs[cur][r * 32 + ((q ^ ((r >> 1) & 3)) << 3)]);
        }
        #pragma unroll
        for (int mi = 0; mi < MR; mi++) {
            #pragma unroll
            for (int ni = 0; ni < NR; ni++)
                acc[mi][ni] = __builtin_amdgcn_mfma_f32_16x16x32_bf16(af[mi], bfr[ni], acc[mi][ni], 0, 0, 0);
        }
        asm volatile("s_waitcnt vmcnt(0)" ::: "memory");
        __builtin_amdgcn_s_barrier();
        cur ^= 1;
    }
    float* pdb = pd + (size_t)b * N_ * N_;
    const int cr = (lane >> 4) * 4, cc = lane & 15;
    #pragma unroll
    for (int mi = 0; mi < MR; mi++) {
        #pragma unroll
        for (int ni = 0; ni < NR; ni++) {
            #pragma unroll
            for (int r = 0; r < 4; r++) {
                const int row = rb + wr + mi * 16 + cr + r;
                const int col = cb + wc + ni * 16 + cc;
                pdb[(size_t)row * N_ + col] = 2.f * acc[mi][ni][r] - xxb[col];
            }
        }
    }
}

// ---------------------------------------------------------------- MFMA bf16 GEMM (device body)
template<int KD, int NC, int TM, int TN, bool CATA, bool POOL, int SPLIT>
__device__ __forceinline__ void gemm_dev(int bx, int by,
                                         const unsigned short* __restrict__ A,
                                         const unsigned short* __restrict__ A2,
                                         const unsigned short* __restrict__ A3,
                                         const unsigned short* __restrict__ A4,
                                         const unsigned short* __restrict__ Bw,
                                         const float* __restrict__ bias,
                                         const float* __restrict__ resid,
                                         float* __restrict__ Cout,
                                         float* __restrict__ Cz, int yco,
                                         int scale_cols, float qs,
                                         const float* __restrict__ gamma,
                                         const float* __restrict__ beta,
                                         unsigned short* __restrict__ obf,
                                         unsigned* __restrict__ pmaxu,
                                         float* __restrict__ psum,
                                         unsigned short* __restrict__ sxa,
                                         unsigned short* __restrict__ sxb,
                                         float* __restrict__ xxo) {
    const int t = threadIdx.x;
    const int rb = bx * TM, cb = by * TN;
    const int w = t >> 6, lane = t & 63;
    constexpr int QR = TM / 2, QC = TN / 2;
    constexpr int MR = QR / 16, NR = QC / 16;
    const int wr = (w & 1) * QR, wc = (w >> 1) * QC;
    const int fr = lane & 15, q = lane >> 4, fq = q * 8;
    f32x4 acc[MR][NR] = {};
    if constexpr (KD % 32 == 0) {
        __shared__ __align__(16) unsigned short As[2][TM * 32];
        __shared__ __align__(16) unsigned short Bs[2][TN * 32];
        auto STAGE = [&](int buf, int k0) {
            const unsigned short* Asrc = A; int AC = KD, ac0 = k0;
            if constexpr (CATA) {
                if (k0 >= 256)      { Asrc = A4; AC = 256; ac0 = k0 - 256; }
                else if (k0 >= 128) { Asrc = A3; AC = 128; ac0 = k0 - 128; }
                else if (k0 >= 64)  { Asrc = A2; AC = 64;  ac0 = k0 - 64; }
                else                { Asrc = A;  AC = 64;  ac0 = k0; }
            }
            constexpr int AT = TM * 4;
            #pragma unroll
            for (int R = 0; R < (AT + 255) / 256; R++) {
                const int G = t + R * 256;
                if (AT >= (R + 1) * 256 || G < AT) {
                    const int m = G >> 2, gs = (G & 3) ^ ((m >> 1) & 3);
                    ldsld16(&Asrc[(size_t)(rb + m) * AC + ac0 + gs * 8], &As[buf][w * 512 + R * 2048]);
                }
            }
            constexpr int BT = TN * 4;
            #pragma unroll
            for (int R = 0; R < (BT + 255) / 256; R++) {
                const int G = t + R * 256;
                if (BT >= (R + 1) * 256 || G < BT) {
                    const int n = G >> 2, gs = (G & 3) ^ ((n >> 1) & 3);
                    ldsld16(&Bw[(size_t)(cb + n) * KD + k0 + gs * 8], &Bs[buf][w * 512 + R * 2048]);
                }
            }
        };
        constexpr int NT = KD / 32;
        STAGE(0, 0);
        asm volatile("s_waitcnt vmcnt(0)" ::: "memory");
        __builtin_amdgcn_s_barrier();
        int cur = 0;
        for (int ts = 0; ts < NT; ++ts) {
            if (ts + 1 < NT) STAGE(cur ^ 1, (ts + 1) * 32);
            short8 af[MR], bfr[NR];
            #pragma unroll
            for (int mi = 0; mi < MR; mi++) {
                const int r = wr + mi * 16 + fr;
                af[mi] = *reinterpret_cast<const short8*>(&As[cur][r * 32 + ((q ^ ((r >> 1) & 3)) << 3)]);
            }
            #pragma unroll
            for (int ni = 0; ni < NR; ni++) {
                const int r = wc + ni * 16 + fr;
                bfr[ni] = *reinterpret_cast<const short8*>(&Bs[cur][r * 32 + ((q ^ ((r >> 1) & 3)) << 3)]);
            }
            #pragma unroll
            for (int mi = 0; mi < MR; mi++) {
                #pragma unroll
                for (int ni = 0; ni < NR; ni++)
                    acc[mi][ni] = __builtin_amdgcn_mfma_f32_16x16x32_bf16(af[mi], bfr[ni], acc[mi][ni], 0, 0, 0);
            }
            asm volatile("s_waitcnt vmcnt(0)" ::: "memory");
            __builtin_amdgcn_s_barrier();
            cur ^= 1;
        }
    } else {
        // fallback (KD=3): reg-staged, padded LDS, scalar guarded loads
        __shared__ __align__(16) unsigned short As[TM * 40];
        __shared__ __align__(16) unsigned short Bs[TN * 40];
        for (int k0 = 0; k0 < KD; k0 += 32) {
            __syncthreads();
            #pragma unroll
            for (int u = t; u < TM * 4; u += 256) {
                const int m = u >> 2, c = (u & 3) * 8;
                #pragma unroll
                for (int j = 0; j < 8; j++) {
                    const int kk = k0 + c + j;
                    As[m * 40 + c + j] = (kk < KD) ? A[(size_t)(rb + m) * KD + kk] : (unsigned short)0;
                }
            }
            #pragma unroll
            for (int u = t; u < TN * 4; u += 256) {
                const int n = u >> 2, c = (u & 3) * 8;
                const int gn = cb + n;
                if (gn < NC) {
                    #pragma unroll
                    for (int j = 0; j < 8; j++) {
                        const int kk = k0 + c + j;
                        Bs[n * 40 + c + j] = (kk < KD) ? Bw[(size_t)gn * KD + kk] : (unsigned short)0;
                    }
                } else {
                    short8 z = {};
                    *reinterpret_cast<short8*>(&Bs[n * 40 + c]) = z;
                }
            }
            __syncthreads();
            short8 af[MR], bfr[NR];
            #pragma unroll
            for (int mi = 0; mi < MR; mi++)
                af[mi] = *reinterpret_cast<const short8*>(&As[(wr + mi * 16 + fr) * 40 + fq]);
            #pragma unroll
            for (int ni = 0; ni < NR; ni++)
                bfr[ni] = *reinterpret_cast<const short8*>(&Bs[(wc + ni * 16 + fr) * 40 + fq]);
            #pragma unroll
            for (int mi = 0; mi < MR; mi++) {
                #pragma unroll
                for (int ni = 0; ni < NR; ni++)
                    acc[mi][ni] = __builtin_amdgcn_mfma_f32_16x16x32_bf16(af[mi], bfr[ni], acc[mi][ni], 0, 0, 0);
            }
        }
    }
    const int cr = (lane >> 4) * 4, cc = lane & 15;
    if constexpr (POOL) {
        const int bidx = rb >> 10;
        #pragma unroll
        for (int ni = 0; ni < NR; ni++) {
            const int col = cb + wc + ni * 16 + cc;
            const float gm = gamma[col] * BN_SCALE, bt = beta[col];
            float sm = 0.f, mxv = -3e38f;
            #pragma unroll
            for (int mi = 0; mi < MR; mi++) {
                #pragma unroll
                for (int r = 0; r < 4; r++) {
                    float v = acc[mi][ni][r] * gm + bt;
                    v = v >= 0.f ? v : 0.2f * v;
                    sm += v; mxv = fmaxf(mxv, v);
                }
            }
            sm += __shfl_xor(sm, 16, 64);
            sm += __shfl_xor(sm, 32, 64);
            mxv = fmaxf(mxv, __shfl_xor(mxv, 16, 64));
            mxv = fmaxf(mxv, __shfl_xor(mxv, 32, 64));
            if (lane < 16) {
                atomicAdd(&psum[bidx * 1024 + col], sm);
                unsigned tb = __float_as_uint(mxv);
                tb = (tb & 0x80000000u) ? ~tb : (tb | 0x80000000u);
                atomicMax(&pmaxu[bidx * 1024 + col], tb);
            }
        }
    } else {
        float sx[MR][4] = {};
        #pragma unroll
        for (int mi = 0; mi < MR; mi++) {
            #pragma unroll
            for (int ni = 0; ni < NR; ni++) {
                #pragma unroll
                for (int r = 0; r < 4; r++) {
                    const int row = rb + wr + mi * 16 + cr + r;
                    const int col = cb + wc + ni * 16 + cc;
                    if (col < NC) {
                        float v = acc[mi][ni][r] + (bias ? bias[col] : 0.f);
                        if (col < scale_cols) v *= qs;
                        if (resid) v += resid[(size_t)row * NC + col];
                        if (gamma) {
                            v = v * (gamma[col] * BN_SCALE) + beta[col];
                            v = v >= 0.f ? v : 0.2f * v;
                        }
                        if (yco > 0) {
                            if (col < yco) Cout[(size_t)row * yco + col] = v;
                            else           Cz[(size_t)row * yco + (col - yco)] = v;
                        } else {
                            Cout[(size_t)row * NC + col] = v;
                        }
                        if (obf) obf[(size_t)row * NC + col] = F2BF(v);
                        if constexpr (SPLIT > 0) {
                            constexpr int KP2 = 3 * SPLIT;
                            const unsigned short h = F2BF(v);
                            const unsigned short l = F2BF(v - US2F(h));
                            sxa[(size_t)row * KP2 + 0 * SPLIT + col] = h;
                            sxa[(size_t)row * KP2 + 1 * SPLIT + col] = l;
                            sxa[(size_t)row * KP2 + 2 * SPLIT + col] = h;
                            sxb[(size_t)row * KP2 + 0 * SPLIT + col] = h;
                            sxb[(size_t)row * KP2 + 1 * SPLIT + col] = h;
                            sxb[(size_t)row * KP2 + 2 * SPLIT + col] = l;
                            sx[mi][r] += v * v;
                        }
                    }
                }
            }
        }
        if constexpr (SPLIT > 0) {
            #pragma unroll
            for (int mi = 0; mi < MR; mi++) {
                #pragma unroll
                for (int r = 0; r < 4; r++) {
                    float s = sx[mi][r];
                    s += __shfl_xor(s, 1, 64);
                    s += __shfl_xor(s, 2, 64);
                    s += __shfl_xor(s, 4, 64);
                    s += __shfl_xor(s, 8, 64);
                    if ((lane & 15) == 0)
                        atomicAdd(&xxo[rb + wr + mi * 16 + cr + r], s);
                }
            }
        }
    }
}

// AFF: remap blockIdx.x so row-block batch == XCD (linear id % 8).
template<int KD, int NC, int TM, int TN, bool CATA = false, bool POOL = false, int SPLIT = 0, bool AFF = false>
__global__ __launch_bounds__(256) void k_gemmb(const unsigned short* __restrict__ A,
                                               const unsigned short* __restrict__ A2,
                                               const unsigned short* __restrict__ A3,
                                               const unsigned short* __restrict__ A4,
                                               const unsigned short* __restrict__ Bw,
                                               const float* __restrict__ bias,
                                               const float* __restrict__ resid,
                                               float* __restrict__ Cout,
                                               int scale_cols, float qs,
                                               const float* __restrict__ gamma,
                                               const float* __restrict__ beta,
                                               unsigned short* __restrict__ obf,
                                               unsigned* __restrict__ pmaxu,
                                               float* __restrict__ psum,
                                               unsigned short* __restrict__ sxa,
                                               unsigned short* __restrict__ sxb,
                                               float* __restrict__ xxo) {
    int bx = blockIdx.x;
    if constexpr (AFF) bx = (bx & 7) * (gridDim.x >> 3) + (bx >> 3);
    gemm_dev<KD, NC, TM, TN, CATA, POOL, SPLIT>(bx, blockIdx.y,
        A, A2, A3, A4, Bw, bias, resid, Cout, nullptr, 0, scale_cols, qs, gamma, beta,
        obf, pmaxu, psum, sxa, sxb, xxo);
}

// ---------------------------------------------------------------- combined pdm || yz-GEMM
// Both depend only on the previous layer's outputs: blocks [0,512) = pdm
// (batch-affine), rest = yz edge-feature gemm (batch-affine remap; routes y/z
// cols to the dense arrays the seledge gather reads from the same XCD's L2).
template<int KP, int KDY, int NCY, int TMY, int TNY>
__global__ __launch_bounds__(256) void k_pdmyz(const unsigned short* __restrict__ xa,
                                               const unsigned short* __restrict__ xb,
                                               const float* __restrict__ xx,
                                               float* __restrict__ pd,
                                               const unsigned short* __restrict__ Ay,
                                               const unsigned short* __restrict__ Bwy,
                                               float* __restrict__ Cy,
                                               float* __restrict__ Cz, int yco, int gxy) {
    if ((int)blockIdx.x < 512) { pdm_dev<KP, 128, 128>(blockIdx.x, xa, xb, xx, pd); return; }
    const int g = blockIdx.x - 512;           // 512 ≡ 0 mod 8 -> XCD = g&7
    const int batch = g & 7, rem = g >> 3;
    const int rpb = gxy >> 3;                 // row-blocks per batch
    const int bx = batch * rpb + rem % rpb;
    const int by = rem / rpb;
    gemm_dev<KDY, NCY, TMY, TNY, false, false, 0>(bx, by,
        Ay, nullptr, nullptr, nullptr, Bwy, nullptr, nullptr, Cy, Cz, yco, 0, 1.f,
        nullptr, nullptr, nullptr, nullptr, nullptr, nullptr, nullptr, nullptr);
}

// ---------------------------------------------------------------- fused top-20 selection + EdgeConv gather
// 2048 blocks (32 waves/CU TLP for the serial 20-round chain -- R5/R6 lesson);
// wave w selects row i0+w's top-20 from pd (local XCD L2), indices go through
// LDS (idx HBM round-trip eliminated), then the block gathers y-rows for its
// 4 points (batch-affine) and applies the max/center/BN/LReLU epilogue.
template<int CO>
__global__ __launch_bounds__(256) void k_seledge(const float* __restrict__ pd,
                                                 const float* __restrict__ y,
                                                 const float* __restrict__ z,
                                                 const float* __restrict__ g,
                                                 const float* __restrict__ bb,
                                                 float* __restrict__ out,
                                                 unsigned short* __restrict__ outb) {
    const int t = threadIdx.x;
    const int w = t >> 6, lane = t & 63;
    const int blk = blockIdx.x;
    const int b = blk & 7;
    const int i0 = (b << 10) + ((blk >> 3) << 2);      // 4 rows per block
    const int bbase = b << 10;
    __shared__ int sidx[4][K_];
    {   // ---- selection (verbatim sel_dev logic, row = i0 + w)
        const int i = i0 + w;
        const float* row = pd + (size_t)b * N_ * N_ + (size_t)(i & 1023) * N_;
        unsigned key[16];
        #pragma unroll
        for (int q = 0; q < 16; q++) {
            const int j = q * 64 + lane;
            unsigned bits = __float_as_uint(row[j]);
            bits = (bits & 0x80000000u) ? ~bits : (bits | 0x80000000u);
            key[q] = (bits & 0xFFFFFC00u) | (unsigned)(N_ - 1 - j);
        }
        int myj = 0;
        for (int kk = 0; kk < K_; kk++) {
            unsigned m = key[0];
            #pragma unroll
            for (int u = 1; u < 16; u++) m = key[u] > m ? key[u] : m;
            #pragma unroll
            for (int s = 1; s < 64; s <<= 1) {
                unsigned o = (unsigned)__shfl_xor((int)m, s, 64);
                m = o > m ? o : m;
            }
            const int j = N_ - 1 - (int)(m & 1023u);
            if (lane == kk) myj = j;
            #pragma unroll
            for (int u = 0; u < 16; u++)
                if (key[u] == m) key[u] = 0u;      // below any plausible real key
        }
        if (lane < K_) sidx[w][lane] = myj;
    }
    __syncthreads();
    // ---- gather + epilogue (old edgemax body, 4 points x CO/4 float4 cols)
    constexpr int TPP = CO / 4;
    if (t < 4 * TPP) {
        const int p = t / TPP;
        const int cw = (t % TPP) * 4;
        const int ig = i0 + p;
        float4 m = {-3e38f, -3e38f, -3e38f, -3e38f};
        #pragma unroll 4
        for (int k = 0; k < K_; k++) {
            const int jg = bbase + sidx[p][k];
            const float4 yv = *reinterpret_cast<const float4*>(&y[(size_t)jg * CO + cw]);
            m.x = fmaxf(m.x, yv.x); m.y = fmaxf(m.y, yv.y);
            m.z = fmaxf(m.z, yv.z); m.w = fmaxf(m.w, yv.w);
        }
        const float4 yi = *reinterpret_cast<const float4*>(&y[(size_t)ig * CO + cw]);
        const float4 zi = *reinterpret_cast<const float4*>(&z[(size_t)ig * CO + cw]);
        const float4 gv = *reinterpret_cast<const float4*>(&g[cw]);
        const float4 bv = *reinterpret_cast<const float4*>(&bb[cw]);
        float vals[4] = {m.x - yi.x + zi.x, m.y - yi.y + zi.y,
                         m.z - yi.z + zi.z, m.w - yi.w + zi.w};
        float gs[4] = {gv.x, gv.y, gv.z, gv.w};
        float bs[4] = {bv.x, bv.y, bv.z, bv.w};
        float4 o;
        float* op = &o.x;
        #pragma unroll
        for (int j = 0; j < 4; j++) {
            float h = vals[j] * (gs[j] * BN_SCALE) + bs[j];
            op[j] = h >= 0.f ? h : 0.2f * h;
        }
        *reinterpret_cast<float4*>(&out[(size_t)ig * CO + cw]) = o;
        #pragma unroll
        for (int j = 0; j < 4; j++) outb[(size_t)ig * CO + cw + j] = F2BF(op[j]);
    }
}

// ---------------------------------------------------------------- attention (layer 4 only)
// R13 lesson: the scalar E=256 out-proj fusion (k_attnout4) ran at 85us --
// VALU-bound with LDS chunk reloads.  Scalar out-proj only beats MFMA+boundary
// when wo fits LDS whole (E<=128), so layer 4 keeps attn -> owb -> MFMA gemm.
template<int E>
__global__ __launch_bounds__(256) void k_attn(const float* __restrict__ qkv,
                                              unsigned short* __restrict__ o) {
    constexpr int H = 4, D = E / H, L = 8;
    const int n = blockIdx.x;
    const int t = threadIdx.x;
    const int h = t >> 6, lane = t & 63;
    __shared__ float sq[L][3 * E];
    __shared__ float so[L][E];
    for (int u = t; u < L * 3 * E; u += 256) {
        int l = u / (3 * E), r = u - l * (3 * E);
        sq[l][r] = qkv[(size_t)(l * N_ + n) * (3 * E) + r];
    }
    __syncthreads();
    const int l = lane >> 3, m = lane & 7;
    float s = 0.f;
    #pragma unroll 8
    for (int dd = 0; dd < D; dd++)
        s += sq[l][h * D + dd] * sq[m][E + h * D + dd];
    float mx = s;
    #pragma unroll
    for (int st = 1; st < 8; st <<= 1) mx = fmaxf(mx, __shfl_xor(mx, st, 64));
    float e = expf(s - mx);
    float sum = e;
    #pragma unroll
    for (int st = 1; st < 8; st <<= 1) sum += __shfl_xor(sum, st, 64);
    const float p = e / sum;
    float pm[8];
    #pragma unroll
    for (int mm = 0; mm < 8; mm++) pm[mm] = __shfl(p, (lane & 56) | mm, 64);
    #pragma unroll
    for (int j = 0; j < D / 8; j++) {
        const int dd = m + 8 * j;
        float a = 0.f;
        #pragma unroll
        for (int mm = 0; mm < 8; mm++) a += pm[mm] * sq[mm][2 * E + h * D + dd];
        so[l][h * D + dd] = a;
    }
    __syncthreads();
    for (int u = t; u < L * E; u += 256) {
        int l2 = u / E, e2 = u - l2 * E;
        o[(size_t)(l2 * N_ + n) * E + e2] = F2BF(so[l2][e2]);
    }
}

// ---------------------------------------------------------------- fused attention + out-proj (layers 1-3)
template<int E, int SPLIT>
__global__ __launch_bounds__(256) void k_attnout(const float* __restrict__ qkv,
                                                 const unsigned short* __restrict__ wo,
                                                 const float* __restrict__ bo,
                                                 float* __restrict__ x,
                                                 unsigned short* __restrict__ xob,
                                                 unsigned short* __restrict__ sxa,
                                                 unsigned short* __restrict__ sxb,
                                                 float* __restrict__ xxo) {
    constexpr int H = 4, D = E / H, L = 8;
    const int n = blockIdx.x;
    const int t = threadIdx.x;
    const int h = t >> 6, lane = t & 63;
    __shared__ float sq[L][3 * E];
    __shared__ float so[L][E];
    __shared__ unsigned short swo[E][E + 8];
    __shared__ float sxx[L];
    for (int u = t; u < L * 3 * E; u += 256) {
        int l = u / (3 * E), r = u - l * (3 * E);
        sq[l][r] = qkv[(size_t)(l * N_ + n) * (3 * E) + r];
    }
    for (int u = t; u < E * E; u += 256) swo[u / E][u % E] = wo[u];
    if (t < L) sxx[t] = 0.f;
    __syncthreads();
    const int l = lane >> 3, m = lane & 7;
    float s = 0.f;
    #pragma unroll 8
    for (int dd = 0; dd < D; dd++)
        s += sq[l][h * D + dd] * sq[m][E + h * D + dd];
    float mx = s;
    #pragma unroll
    for (int st = 1; st < 8; st <<= 1) mx = fmaxf(mx, __shfl_xor(mx, st, 64));
    float e = expf(s - mx);
    float sum = e;
    #pragma unroll
    for (int st = 1; st < 8; st <<= 1) sum += __shfl_xor(sum, st, 64);
    const float p = e / sum;
    float pm[8];
    #pragma unroll
    for (int mm = 0; mm < 8; mm++) pm[mm] = __shfl(p, (lane & 56) | mm, 64);
    #pragma unroll
    for (int j = 0; j < D / 8; j++) {
        const int dd = m + 8 * j;
        float a = 0.f;
        #pragma unroll
        for (int mm = 0; mm < 8; mm++) a += pm[mm] * sq[mm][2 * E + h * D + dd];
        so[l][h * D + dd] = a;
    }
    __syncthreads();
    for (int u = t; u < L * E; u += 256)
        so[u / E][u % E] = US2F(F2BF(so[u / E][u % E]));
    __syncthreads();
    constexpr int PT = (L * E) / 256;
    #pragma unroll
    for (int it = 0; it < PT; it++) {
        const int item = t + it * 256;
        const int ll = item / E, ee = item % E;
        float acc = 0.f;
        #pragma unroll 16
        for (int c = 0; c < E; c++)
            acc += so[ll][c] * US2F(swo[ee][c]);
        const int row = ll * N_ + n;
        const float v = acc + bo[ee] + x[(size_t)row * E + ee];
        x[(size_t)row * E + ee] = v;
        xob[(size_t)row * E + ee] = F2BF(v);
        if constexpr (SPLIT > 0) {
            constexpr int KP2 = 3 * SPLIT;
            const unsigned short hh = F2BF(v);
            const unsigned short lo = F2BF(v - US2F(hh));
            sxa[(size_t)row * KP2 + 0 * SPLIT + ee] = hh;
            sxa[(size_t)row * KP2 + 1 * SPLIT + ee] = lo;
            sxa[(size_t)row * KP2 + 2 * SPLIT + ee] = hh;
            sxb[(size_t)row * KP2 + 0 * SPLIT + ee] = hh;
            sxb[(size_t)row * KP2 + 1 * SPLIT + ee] = hh;
            sxb[(size_t)row * KP2 + 2 * SPLIT + ee] = lo;
            float vs = v * v;
            #pragma unroll
            for (int st = 1; st < 64; st <<= 1) vs += __shfl_xor(vs, st, 64);
            if (lane == 0) atomicAdd(&sxx[ll], vs);
        }
    }
    if constexpr (SPLIT > 0) {
        __syncthreads();
        if (t < L) xxo[t * N_ + n] = sxx[t];
    }
}

// ---------------------------------------------------------------- FC head
__global__ __launch_bounds__(256) void k_fc1(const unsigned* __restrict__ pmaxu,
                                             const float* __restrict__ psum,
                                             const float* __restrict__ l1wT,
                                             const float* __restrict__ g6, const float* __restrict__ b6,
                                             float* __restrict__ f1) {
    int oc = blockIdx.x, b = blockIdx.y, t = threadIdx.x;
    __shared__ float fin[2048];
    __shared__ float ps[4][64];
    for (int u = t; u < 2048; u += 256) {
        float v;
        if (u < 1024) {
            unsigned tb = pmaxu[b * 1024 + u];
            unsigned bits = (tb & 0x80000000u) ? (tb & 0x7FFFFFFFu) : ~tb;
            v = __uint_as_float(bits);
        } else {
            v = psum[b * 1024 + (u - 1024)] * (1.f / 1024.f);
        }
        fin[u] = v;
    }
    __syncthreads();
    int ol = t & 63, kc = t >> 6;
    int o = oc * 64 + ol;
    float acc = 0.f;
    for (int c = kc * 512; c < kc * 512 + 512; c++) acc += fin[c] * l1wT[(size_t)c * 512 + o];
    ps[kc][ol] = acc;
    __syncthreads();
    if (t < 64) {
        int oo = oc * 64 + t;
        float a = ps[0][t] + ps[1][t] + ps[2][t] + ps[3][t];
        float h = a * (g6[oo] * BN_SCALE) + b6[oo];
        f1[b * 512 + oo] = h >= 0.f ? h : 0.2f * h;
    }
}

__global__ __launch_bounds__(256) void k_fc23(const float* __restrict__ f1, const float* __restrict__ l2wT,
                                              const float* __restrict__ l2b,
                                              const float* __restrict__ g7, const float* __restrict__ b7,
                                              const float* __restrict__ l3wT, const float* __restrict__ l3b,
                                              void* __restrict__ out, DetP dp) {
    int b = blockIdx.x, t = threadIdx.x;
    __shared__ float fin[512];
    __shared__ float f2s[256];
    __shared__ int sbf;
    if (t == 0) sbf = det_isbf(dp);
    for (int u = t; u < 512; u += 256) fin[u] = f1[b * 512 + u];
    __syncthreads();
    {
        float acc = 0.f;
        for (int c = 0; c < 512; c++) acc += fin[c] * l2wT[(size_t)c * 256 + t];
        acc += l2b[t];
        float h = acc * (g7[t] * BN_SCALE) + b7[t];
        f2s[t] = h >= 0.f ? h : 0.2f * h;
    }
    __syncthreads();
    if (t < 40) {
        float acc = 0.f;
        for (int c = 0; c < 256; c++) acc += f2s[c] * l3wT[(size_t)c * 40 + t];
        acc += l3b[t];
        if (sbf) ((__hip_bfloat16*)out)[b * 40 + t] = __float2bfloat16(acc);
        else     ((float*)out)[b * 40 + t] = acc;
    }
}

// ================================================================ host
extern "C" void kernel_launch(void* const* d_in, const int* in_sizes, int n_in,
                              void* d_out, int out_size, void* d_ws, size_t ws_size,
                              hipStream_t stream) {
    auto us = [&](int i) { return (const unsigned short*)d_in[i]; };

    float* ws = (float*)d_ws;
    size_t off = 0;
    auto A = [&](size_t n) { float* p = ws + off; off += (n + 3) & ~(size_t)3; return p; };
    auto AU = [&](size_t n) { return (unsigned short*)A((n + 1) / 2); };
    float* x1   = A((size_t)BN_ * 64);
    float* x2   = A((size_t)BN_ * 64);
    float* x3   = A((size_t)BN_ * 128);
    float* x4   = A((size_t)BN_ * 256);
    float* pd   = A((size_t)BN_ * 1024);   // pd scratch
    float* f1   = A(8 * 512);
    float* xx   = A(4 * BN_);              // per-layer row norms
    float* qkvw = A((size_t)BN_ * 768);    // qkv / y,z scratch
    // dedicated kNN split buffers (k_attnout reads qkvw while writing these)
    unsigned short* xa = AU((size_t)BN_ * 384);
    unsigned short* xb = AU((size_t)BN_ * 384);
    // bf16 activation copies
    unsigned short* xf0b = AU((size_t)BN_ * 3);
    unsigned short* x1b  = AU((size_t)BN_ * 64);
    unsigned short* x2b  = AU((size_t)BN_ * 64);
    unsigned short* x3b  = AU((size_t)BN_ * 128);
    unsigned short* x4b  = AU((size_t)BN_ * 256);
    unsigned short* owb  = AU((size_t)BN_ * 256);   // layer-4 attn output
    // pooled reductions (conv5 fused epilogue) -- contiguous, zeroed by k_prep
    unsigned* pmaxu = (unsigned*)A(8 * 1024);
    float*    psum  = A(8 * 1024);
    // bf16 weights (n,k) layouts
    unsigned short* w1yzb = AU(128 * 3);
    unsigned short* w2yzb = AU(128 * 64);
    unsigned short* w3yzb = AU(256 * 64);
    unsigned short* w4yzb = AU(512 * 128);
    unsigned short* a1wib = AU(192 * 64);  unsigned short* a1wob = AU(64 * 64);
    unsigned short* a2wib = AU(192 * 64);  unsigned short* a2wob = AU(64 * 64);
    unsigned short* a3wib = AU(384 * 128); unsigned short* a3wob = AU(128 * 128);
    unsigned short* a4wib = AU(768 * 256); unsigned short* a4wob = AU(256 * 256);
    unsigned short* w5b   = AU(1024 * 512);
    // fp32 fc weights (transposed)
    float* l1wT  = A(2048 * 512);
    float* l2wT  = A(512 * 256);
    float* l3wT  = A(256 * 40);
    // converted vectors (fp32)
    float* g1f = A(64);   float* b1f = A(64);
    float* g2f = A(64);   float* b2f = A(64);
    float* g3f = A(128);  float* b3f = A(128);
    float* g4f = A(256);  float* b4f = A(256);
    float* bi1 = A(192);  float* bo1 = A(64);
    float* bi2 = A(192);  float* bo2 = A(64);
    float* bi3 = A(384);  float* bo3 = A(128);
    float* bi4 = A(768);  float* bo4 = A(256);
    float* g5f = A(1024); float* b5f = A(1024);
    float* g6f = A(512);  float* b6f = A(512);
    float* l2bf = A(256);
    float* g7f = A(256);  float* b7f = A(256);
    float* l3bf = A(40);

    float* xx1 = xx;              float* xx2 = xx + BN_;
    float* xx3 = xx + 2 * BN_;    float* xx4 = xx + 3 * BN_;

    // y/z edge-feature arrays alias qkvw (qkv gemm later overwrites)
    float* yy = qkvw;
    float* zz = qkvw + (size_t)BN_ * 256;

    DetP dp{{us(2), us(5), us(8), us(11), us(30), us(33), us(37)}};

    TList tl; int nb = 0; int k = 0;
    auto add = [&](int i, void* dst, int O, int I, int mode) {
        tl.p[k].src = d_in[i]; tl.p[k].dst = dst; tl.p[k].O = O; tl.p[k].I = I;
        tl.p[k].blk0 = nb; tl.p[k].mode = mode;
        nb += (O * I + 255) / 256; k++;
    };
    add(0,  xf0b,  BN_ * 3, 1, 2);
    add(0,  pmaxu, 16384, 1, 4);      // zero pmaxu+psum (contiguous)
    add(1,  w1yzb, 64, 6, 3);
    add(4,  w2yzb, 64, 128, 3);
    add(7,  w3yzb, 128, 128, 3);
    add(10, w4yzb, 256, 256, 3);
    add(13, a1wib, 192, 64, 2);
    add(15, a1wob, 64, 64, 2);
    add(17, a2wib, 192, 64, 2);
    add(19, a2wob, 64, 64, 2);
    add(21, a3wib, 384, 128, 2);
    add(23, a3wob, 128, 128, 2);
    add(25, a4wib, 768, 256, 2);
    add(27, a4wob, 256, 256, 2);
    add(29, w5b,   1024, 512, 2);
    add(2,  g1f, 64, 1, 0);   add(3,  b1f, 64, 1, 0);
    add(5,  g2f, 64, 1, 0);   add(6,  b2f, 64, 1, 0);
    add(8,  g3f, 128, 1, 0);  add(9,  b3f, 128, 1, 0);
    add(11, g4f, 256, 1, 0);  add(12, b4f, 256, 1, 0);
    add(14, bi1, 192, 1, 0);  add(16, bo1, 64, 1, 0);
    add(18, bi2, 192, 1, 0);  add(20, bo2, 64, 1, 0);
    add(22, bi3, 384, 1, 0);  add(24, bo3, 128, 1, 0);
    add(26, bi4, 768, 1, 0);  add(28, bo4, 256, 1, 0);
    add(30, g5f, 1024, 1, 0); add(31, b5f, 1024, 1, 0);
    add(33, g6f, 512, 1, 0);  add(34, b6f, 512, 1, 0);
    add(36, l2bf, 256, 1, 0);
    add(37, g7f, 256, 1, 0);  add(38, b7f, 256, 1, 0);
    add(40, l3bf, 40, 1, 0);

    // FC-weight transposes + layer-1 split/norms fused into k_prep tail blocks
    TrP tp1{d_in[32], l1wT, 512, 2048, 2048 / 32, 0};
    TrP tp2{d_in[35], l2wT, 256, 512,  512 / 32,  (2048 / 32) * (512 / 32)};
    TrP tp3{d_in[39], l3wT, 40,  256,  256 / 32,  tp2.blk0 + (512 / 32) * (256 / 32)};
    const int trblocks = tp3.blk0 + (256 / 32) * ((40 + 31) / 32);
    const int splblocks = (BN_ * 32) / 256 + 32;   // split + norms
    k_prep<<<nb + trblocks + splblocks, 256, 0, stream>>>(
        tl, k, tp1, tp2, tp3, nb, trblocks, d_in[0], dp, xa, xb, xx1);

    const unsigned short* N0 = nullptr;
    unsigned short* U0 = nullptr;
    unsigned* NU = nullptr; float* NF = nullptr;

    // layer 1  (C=3 -> 64)
    k_pdmyz<32, 3, 128, 64, 64><<<512 + 256, 256, 0, stream>>>(xa, xb, xx1, pd, xf0b, w1yzb, yy, zz, 64, 128);
    k_seledge<64><<<2048, 256, 0, stream>>>(pd, yy, zz, g1f, b1f, x1, x1b);
    k_gemmb<64, 192, 64, 64, false, false, 0, true><<<dim3(128, 3), 256, 0, stream>>>(x1b, N0, N0, N0, a1wib, bi1, nullptr, qkvw, 64, 0.25f, nullptr, nullptr, nullptr, NU, NF, U0, U0, NF);
    k_attnout<64, 64><<<N_, 256, 0, stream>>>(qkvw, a1wob, bo1, x1, x1b, xa, xb, xx2);

    // layer 2  (C=64 -> 64, KP=192)
    k_pdmyz<192, 64, 128, 64, 64><<<512 + 256, 256, 0, stream>>>(xa, xb, xx2, pd, x1b, w2yzb, yy, zz, 64, 128);
    k_seledge<64><<<2048, 256, 0, stream>>>(pd, yy, zz, g2f, b2f, x2, x2b);
    k_gemmb<64, 192, 64, 64, false, false, 0, true><<<dim3(128, 3), 256, 0, stream>>>(x2b, N0, N0, N0, a2wib, bi2, nullptr, qkvw, 64, 0.25f, nullptr, nullptr, nullptr, NU, NF, U0, U0, NF);
    k_attnout<64, 64><<<N_, 256, 0, stream>>>(qkvw, a2wob, bo2, x2, x2b, xa, xb, xx3);

    // layer 3  (C=64 -> 128, KP=192)
    k_pdmyz<192, 64, 256, 64, 64><<<512 + 512, 256, 0, stream>>>(xa, xb, xx3, pd, x2b, w3yzb, yy, zz, 128, 128);
    k_seledge<128><<<2048, 256, 0, stream>>>(pd, yy, zz, g3f, b3f, x3, x3b);
    k_gemmb<128, 384, 64, 128, false, false, 0, true><<<dim3(128, 3), 256, 0, stream>>>(x3b, N0, N0, N0, a3wib, bi3, nullptr, qkvw, 128, 0.17677669529663687f, nullptr, nullptr, nullptr, NU, NF, U0, U0, NF);
    k_attnout<128, 128><<<N_, 256, 0, stream>>>(qkvw, a3wob, bo3, x3, x3b, xa, xb, xx4);

    // layer 4  (C=128 -> 256, KP=384; E=256 keeps attn -> owb -> MFMA out-proj)
    k_pdmyz<384, 128, 512, 128, 128><<<512 + 256, 256, 0, stream>>>(xa, xb, xx4, pd, x3b, w4yzb, yy, zz, 256, 64);
    k_seledge<256><<<2048, 256, 0, stream>>>(pd, yy, zz, g4f, b4f, x4, x4b);
    k_gemmb<256, 768, 64, 128, false, false, 0, true><<<dim3(128, 6), 256, 0, stream>>>(x4b, N0, N0, N0, a4wib, bi4, nullptr, qkvw, 256, 0.125f, nullptr, nullptr, nullptr, NU, NF, U0, U0, NF);
    k_attn<256><<<N_, 256, 0, stream>>>(qkvw, owb);
    k_gemmb<256, 256, 64, 128, false, false, 0, true><<<dim3(128, 2), 256, 0, stream>>>(owb, N0, N0, N0, a4wob, bo4, x4, x4, 0, 1.f, nullptr, nullptr, x4b, NU, NF, U0, U0, NF);

    // head: conv5 with fused concat-A and fused pooling epilogue (batch-affine)
    k_gemmb<512, 1024, 128, 128, true, true, 0, true><<<dim3(64, 8), 256, 0, stream>>>(
        x1b, x2b, x3b, x4b, w5b, nullptr, nullptr, nullptr, 0, 1.f, g5f, b5f, nullptr, pmaxu, psum, U0, U0, NF);
    k_fc1<<<dim3(8, 8), 256, 0, stream>>>(pmaxu, psum, l1wT, g6f, b6f, f1);
    k_fc23<<<8, 256, 0, stream>>>(f1, l2wT, l2bf, g7f, b7f, l3wT, l3bf, d_out, dp);
}

// Round 15
// 472.127 us; speedup vs baseline: 1.1013x; 1.0082x over previous
//
#include <hip/hip_runtime.h>
#include <hip/hip_bf16.h>

#define B_ 8
#define N_ 1024
#define K_ 20
#define BN_ (B_*N_)

#define BN_SCALE 0.9999950000374997f

typedef __attribute__((ext_vector_type(8))) short short8;
typedef __attribute__((ext_vector_type(4))) float f32x4;

__device__ __forceinline__ float US2F(unsigned short u) {
    union { unsigned u; float f; } c; c.u = ((unsigned)u) << 16; return c.f;
}
__device__ __forceinline__ unsigned short F2BF(float f) {   // RNE fp32->bf16
    union { float f; unsigned u; } c; c.f = f;
    unsigned r = c.u + 0x7FFF + ((c.u >> 16) & 1);
    return (unsigned short)(r >> 16);
}

// async global->LDS 16B DMA: LDS dest = wave-uniform base + lane*16 (linear);
// global source is per-lane (pre-swizzled there when a swizzled layout is wanted).
__device__ __forceinline__ void ldsld16(const unsigned short* g, unsigned short* l) {
    __builtin_amdgcn_global_load_lds(
        (const __attribute__((address_space(1))) void*)g,
        (__attribute__((address_space(3))) void*)l, 16, 0, 0);
}

// dtype-detect data: first element of 7 gamma vectors (bf16 gammas ~1.0)
struct DetP { const unsigned short* g[7]; };
__device__ __forceinline__ int det_isbf(const DetP& dp) {
    int cnt = 0;
    #pragma unroll
    for (int i = 0; i < 7; i++) {
        float v = US2F(dp.g[i][0]);
        if (v > 0.5f && v < 1.5f) cnt++;
    }
    return cnt >= 4;
}

// ---------------------------------------------------------------- prep primitives
// mode 0: fp32 copy (I==1 -> contiguous).  mode 2: bf16 copy.
// mode 3: edge pair -> bf16 (2O,C).  mode 4: zero-fill fp32.
// Work-packing (R15): independent weight-conversion work is appended as aux
// block regions to the layer-1 pdmyz/seledge launches (stream serialization
// guarantees each item lands >=1 launch before its consumer), filling CU
// tail-time instead of a long standalone k_prep.
struct TPar { const void* src; void* dst; int O, I, blk0, mode; };
struct TList { TPar p[32]; };
struct TrP { const void* src; float* dst; int O, I, bx, blk0; };

__device__ __forceinline__ void prep_entry(const TList& tl, int nent, int blk, int isbf) {
    int wi = 0;
    for (int j = nent - 1; j >= 0; j--) { if (blk >= tl.p[j].blk0) { wi = j; break; } }
    const TPar p = tl.p[wi];
    int e = (blk - p.blk0) * 256 + threadIdx.x;
    int n = p.O * p.I;
    if (e >= n) return;
    if (p.mode == 4) { ((float*)p.dst)[e] = 0.f; return; }
    int o = e / p.I, i = e - o * p.I;
    float v = isbf ? US2F(((const unsigned short*)p.src)[e])
                   : ((const float*)p.src)[e];
    if (p.mode == 0) {
        ((float*)p.dst)[(size_t)i * p.O + o] = v;
    } else if (p.mode == 2) {
        ((unsigned short*)p.dst)[e] = F2BF(v);
    } else {
        const int C = p.I >> 1;
        if (i < C) ((unsigned short*)p.dst)[(size_t)o * C + i] = F2BF(v);
        else       ((unsigned short*)p.dst)[(size_t)(p.O + o) * C + (i - C)] = F2BF(v);
    }
}

// LDS-tiled 32x32 fp32 transpose (coalesced both sides); block-uniform entry.
__device__ __forceinline__ void tr_entry(const TrP& p, int blk, int isbf) {
    const int tx = threadIdx.x & 31, ty = threadIdx.x >> 5;   // 32 x 8
    const int bi = blk % p.bx, bo = blk / p.bx;
    const int i0 = bi * 32, o0 = bo * 32;
    __shared__ float s[32][33];
    #pragma unroll
    for (int r = 0; r < 4; r++) {
        const int o = o0 + ty + r * 8, i = i0 + tx;
        if (o < p.O && i < p.I) {
            const size_t e = (size_t)o * p.I + i;
            s[ty + r * 8][tx] = isbf ? US2F(((const unsigned short*)p.src)[e])
                                     : ((const float*)p.src)[e];
        }
    }
    __syncthreads();
    #pragma unroll
    for (int r = 0; r < 4; r++) {
        const int i = i0 + ty + r * 8, o = o0 + tx;
        if (i < p.I && o < p.O) p.dst[(size_t)i * p.O + o] = s[tx][ty + r * 8];
    }
}

// ---------------------------------------------------------------- prep (critical path only)
// Region 1 [0,nbp): critical table entries (input, L1 weights, zeros, vectors).
// Region 2 [nbp,nbp+nbtr): l2wT/l3wT transposes (small).
// Region 3: layer-1 kNN split (C=3, KP=32, 3-seg) + row norms xx1.
__global__ __launch_bounds__(256) void k_prep(TList tl, int nent,
                                              TrP q0, TrP q1,
                                              int nbp, int nbtr,
                                              const void* x0, DetP dp,
                                              unsigned short* __restrict__ xa,
                                              unsigned short* __restrict__ xb,
                                              float* __restrict__ xx1) {
    __shared__ int sbf;
    if (threadIdx.x == 0) sbf = det_isbf(dp);
    __syncthreads();
    const int isbf = sbf;
    auto ld0 = [&](int idx) {
        return isbf ? US2F(((const unsigned short*)x0)[idx])
                    : ((const float*)x0)[idx];
    };
    const int bid = blockIdx.x;
    if (bid >= nbp + nbtr) {               // ---- region 3: L1 split + norms
        int blk = bid - nbp - nbtr;
        if (blk >= (BN_ * 32) / 256) {     // norms (32 blocks)
            int i = (blk - (BN_ * 32) / 256) * 256 + threadIdx.x;
            if (i >= BN_) return;
            float s = 0.f;
            #pragma unroll
            for (int c = 0; c < 3; c++) { float v = ld0(i * 3 + c); s += v * v; }
            xx1[i] = s;
            return;
        }
        const int e = blk * 256 + threadIdx.x;   // e < BN_*32
        const int i = e >> 5, p = e & 31;
        unsigned short va = 0, vb = 0;
        if (p < 9) {                        // 3 segs x C=3
            const int seg = p / 3, c = p - seg * 3;
            const float v = ld0(i * 3 + c);
            const unsigned short h = F2BF(v);
            const unsigned short l = F2BF(v - US2F(h));
            va = (seg == 1) ? l : h;        // hi,lo,hi
            vb = (seg < 2) ? h : l;         // hi,hi,lo
        }
        xa[e] = va; xb[e] = vb;
        return;
    }
    if (bid >= nbp) {                      // ---- region 2: small transposes
        int blk = bid - nbp;
        if (blk >= q1.blk0) tr_entry(q1, blk - q1.blk0, isbf);
        else                tr_entry(q0, blk, isbf);
        return;
    }
    prep_entry(tl, nent, bid, isbf);       // ---- region 1
}

// ---------------------------------------------------------------- kNN phase 1 (device body)
// pd[b][i][j] = 2*dot(xa_i, xb_j) - xx_j.  3-seg exact-split over KP=3C.
// Batch-affine: batch = bid&7 -> pd stays in the local XCD L2 for seledge.
template<int KP, int TM, int TN>
__device__ __forceinline__ void pdm_dev(int bid,
                                        const unsigned short* __restrict__ xa,
                                        const unsigned short* __restrict__ xb,
                                        const float* __restrict__ xx,
                                        float* __restrict__ pd) {
    const int b = bid & 7;
    const int tt = bid >> 3;                 // 0..63 tile index within batch
    const int rb = (tt >> 3) * TM, cb = (tt & 7) * TN;
    const unsigned short* Ab = xa + (size_t)b * N_ * KP;
    const unsigned short* Bb = xb + (size_t)b * N_ * KP;
    const float* xxb = xx + (size_t)b * N_;
    const int t = threadIdx.x;
    __shared__ __align__(16) unsigned short As[2][TM * 32];
    __shared__ __align__(16) unsigned short Bs[2][TN * 32];
    const int w = t >> 6, lane = t & 63;
    constexpr int QR = TM / 2, QC = TN / 2;
    constexpr int MR = QR / 16, NR = QC / 16;
    const int wr = (w & 1) * QR, wc = (w >> 1) * QC;
    const int fr = lane & 15, q = lane >> 4;
    f32x4 acc[MR][NR] = {};

    auto STAGE = [&](int buf, int k0) {
        constexpr int AT = TM * 4;
        #pragma unroll
        for (int R = 0; R < (AT + 255) / 256; R++) {
            const int G = t + R * 256;
            if (AT >= (R + 1) * 256 || G < AT) {
                const int m = G >> 2, gs = (G & 3) ^ ((m >> 1) & 3);
                ldsld16(&Ab[(size_t)(rb + m) * KP + k0 + gs * 8], &As[buf][w * 512 + R * 2048]);
            }
        }
        constexpr int BT = TN * 4;
        #pragma unroll
        for (int R = 0; R < (BT + 255) / 256; R++) {
            const int G = t + R * 256;
            if (BT >= (R + 1) * 256 || G < BT) {
                const int n = G >> 2, gs = (G & 3) ^ ((n >> 1) & 3);
                ldsld16(&Bb[(size_t)(cb + n) * KP + k0 + gs * 8], &Bs[buf][w * 512 + R * 2048]);
            }
        }
    };

    constexpr int NT = KP / 32;
    STAGE(0, 0);
    asm volatile("s_waitcnt vmcnt(0)" ::: "memory");
    __builtin_amdgcn_s_barrier();
    int cur = 0;
    for (int ts = 0; ts < NT; ++ts) {
        if (ts + 1 < NT) STAGE(cur ^ 1, (ts + 1) * 32);
        short8 af[MR], bfr[NR];
        #pragma unroll
        for (int mi = 0; mi < MR; mi++) {
            const int r = wr + mi * 16 + fr;
            af[mi] = *reinterpret_cast<const short8*>(&As[cur][r * 32 + ((q ^ ((r >> 1) & 3)) << 3)]);
        }
        #pragma unroll
        for (int ni = 0; ni < NR; ni++) {
            const int r = wc + ni * 16 + fr;
            bfr[ni] = *reinterpret_cast<const short8*>(&Bs[cur][r * 32 + ((q ^ ((r >> 1) & 3)) << 3)]);
        }
        #pragma unroll
        for (int mi = 0; mi < MR; mi++) {
            #pragma unroll
            for (int ni = 0; ni < NR; ni++)
                acc[mi][ni] = __builtin_amdgcn_mfma_f32_16x16x32_bf16(af[mi], bfr[ni], acc[mi][ni], 0, 0, 0);
        }
        asm volatile("s_waitcnt vmcnt(0)" ::: "memory");
        __builtin_amdgcn_s_barrier();
        cur ^= 1;
    }
    float* pdb = pd + (size_t)b * N_ * N_;
    const int cr = (lane >> 4) * 4, cc = lane & 15;
    #pragma unroll
    for (int mi = 0; mi < MR; mi++) {
        #pragma unroll
        for (int ni = 0; ni < NR; ni++) {
            #pragma unroll
            for (int r = 0; r < 4; r++) {
                const int row = rb + wr + mi * 16 + cr + r;
                const int col = cb + wc + ni * 16 + cc;
                pdb[(size_t)row * N_ + col] = 2.f * acc[mi][ni][r] - xxb[col];
            }
        }
    }
}

// ---------------------------------------------------------------- MFMA bf16 GEMM (device body)
template<int KD, int NC, int TM, int TN, bool CATA, bool POOL, int SPLIT>
__device__ __forceinline__ void gemm_dev(int bx, int by,
                                         const unsigned short* __restrict__ A,
                                         const unsigned short* __restrict__ A2,
                                         const unsigned short* __restrict__ A3,
                                         const unsigned short* __restrict__ A4,
                                         const unsigned short* __restrict__ Bw,
                                         const float* __restrict__ bias,
                                         const float* __restrict__ resid,
                                         float* __restrict__ Cout,
                                         float* __restrict__ Cz, int yco,
                                         int scale_cols, float qs,
                                         const float* __restrict__ gamma,
                                         const float* __restrict__ beta,
                                         unsigned short* __restrict__ obf,
                                         unsigned* __restrict__ pmaxu,
                                         float* __restrict__ psum,
                                         unsigned short* __restrict__ sxa,
                                         unsigned short* __restrict__ sxb,
                                         float* __restrict__ xxo) {
    const int t = threadIdx.x;
    const int rb = bx * TM, cb = by * TN;
    const int w = t >> 6, lane = t & 63;
    constexpr int QR = TM / 2, QC = TN / 2;
    constexpr int MR = QR / 16, NR = QC / 16;
    const int wr = (w & 1) * QR, wc = (w >> 1) * QC;
    const int fr = lane & 15, q = lane >> 4, fq = q * 8;
    f32x4 acc[MR][NR] = {};
    if constexpr (KD % 32 == 0) {
        __shared__ __align__(16) unsigned short As[2][TM * 32];
        __shared__ __align__(16) unsigned short Bs[2][TN * 32];
        auto STAGE = [&](int buf, int k0) {
            const unsigned short* Asrc = A; int AC = KD, ac0 = k0;
            if constexpr (CATA) {
                if (k0 >= 256)      { Asrc = A4; AC = 256; ac0 = k0 - 256; }
                else if (k0 >= 128) { Asrc = A3; AC = 128; ac0 = k0 - 128; }
                else if (k0 >= 64)  { Asrc = A2; AC = 64;  ac0 = k0 - 64; }
                else                { Asrc = A;  AC = 64;  ac0 = k0; }
            }
            constexpr int AT = TM * 4;
            #pragma unroll
            for (int R = 0; R < (AT + 255) / 256; R++) {
                const int G = t + R * 256;
                if (AT >= (R + 1) * 256 || G < AT) {
                    const int m = G >> 2, gs = (G & 3) ^ ((m >> 1) & 3);
                    ldsld16(&Asrc[(size_t)(rb + m) * AC + ac0 + gs * 8], &As[buf][w * 512 + R * 2048]);
                }
            }
            constexpr int BT = TN * 4;
            #pragma unroll
            for (int R = 0; R < (BT + 255) / 256; R++) {
                const int G = t + R * 256;
                if (BT >= (R + 1) * 256 || G < BT) {
                    const int n = G >> 2, gs = (G & 3) ^ ((n >> 1) & 3);
                    ldsld16(&Bw[(size_t)(cb + n) * KD + k0 + gs * 8], &Bs[buf][w * 512 + R * 2048]);
                }
            }
        };
        constexpr int NT = KD / 32;
        STAGE(0, 0);
        asm volatile("s_waitcnt vmcnt(0)" ::: "memory");
        __builtin_amdgcn_s_barrier();
        int cur = 0;
        for (int ts = 0; ts < NT; ++ts) {
            if (ts + 1 < NT) STAGE(cur ^ 1, (ts + 1) * 32);
            short8 af[MR], bfr[NR];
            #pragma unroll
            for (int mi = 0; mi < MR; mi++) {
                const int r = wr + mi * 16 + fr;
                af[mi] = *reinterpret_cast<const short8*>(&As[cur][r * 32 + ((q ^ ((r >> 1) & 3)) << 3)]);
            }
            #pragma unroll
            for (int ni = 0; ni < NR; ni++) {
                const int r = wc + ni * 16 + fr;
                bfr[ni] = *reinterpret_cast<const short8*>(&Bs[cur][r * 32 + ((q ^ ((r >> 1) & 3)) << 3)]);
            }
            #pragma unroll
            for (int mi = 0; mi < MR; mi++) {
                #pragma unroll
                for (int ni = 0; ni < NR; ni++)
                    acc[mi][ni] = __builtin_amdgcn_mfma_f32_16x16x32_bf16(af[mi], bfr[ni], acc[mi][ni], 0, 0, 0);
            }
            asm volatile("s_waitcnt vmcnt(0)" ::: "memory");
            __builtin_amdgcn_s_barrier();
            cur ^= 1;
        }
    } else {
        // fallback (KD=3): reg-staged, padded LDS, scalar guarded loads
        __shared__ __align__(16) unsigned short As[TM * 40];
        __shared__ __align__(16) unsigned short Bs[TN * 40];
        for (int k0 = 0; k0 < KD; k0 += 32) {
            __syncthreads();
            #pragma unroll
            for (int u = t; u < TM * 4; u += 256) {
                const int m = u >> 2, c = (u & 3) * 8;
                #pragma unroll
                for (int j = 0; j < 8; j++) {
                    const int kk = k0 + c + j;
                    As[m * 40 + c + j] = (kk < KD) ? A[(size_t)(rb + m) * KD + kk] : (unsigned short)0;
                }
            }
            #pragma unroll
            for (int u = t; u < TN * 4; u += 256) {
                const int n = u >> 2, c = (u & 3) * 8;
                const int gn = cb + n;
                if (gn < NC) {
                    #pragma unroll
                    for (int j = 0; j < 8; j++) {
                        const int kk = k0 + c + j;
                        Bs[n * 40 + c + j] = (kk < KD) ? Bw[(size_t)gn * KD + kk] : (unsigned short)0;
                    }
                } else {
                    short8 z = {};
                    *reinterpret_cast<short8*>(&Bs[n * 40 + c]) = z;
                }
            }
            __syncthreads();
            short8 af[MR], bfr[NR];
            #pragma unroll
            for (int mi = 0; mi < MR; mi++)
                af[mi] = *reinterpret_cast<const short8*>(&As[(wr + mi * 16 + fr) * 40 + fq]);
            #pragma unroll
            for (int ni = 0; ni < NR; ni++)
                bfr[ni] = *reinterpret_cast<const short8*>(&Bs[(wc + ni * 16 + fr) * 40 + fq]);
            #pragma unroll
            for (int mi = 0; mi < MR; mi++) {
                #pragma unroll
                for (int ni = 0; ni < NR; ni++)
                    acc[mi][ni] = __builtin_amdgcn_mfma_f32_16x16x32_bf16(af[mi], bfr[ni], acc[mi][ni], 0, 0, 0);
            }
        }
    }
    const int cr = (lane >> 4) * 4, cc = lane & 15;
    if constexpr (POOL) {
        const int bidx = rb >> 10;
        #pragma unroll
        for (int ni = 0; ni < NR; ni++) {
            const int col = cb + wc + ni * 16 + cc;
            const float gm = gamma[col] * BN_SCALE, bt = beta[col];
            float sm = 0.f, mxv = -3e38f;
            #pragma unroll
            for (int mi = 0; mi < MR; mi++) {
                #pragma unroll
                for (int r = 0; r < 4; r++) {
                    float v = acc[mi][ni][r] * gm + bt;
                    v = v >= 0.f ? v : 0.2f * v;
                    sm += v; mxv = fmaxf(mxv, v);
                }
            }
            sm += __shfl_xor(sm, 16, 64);
            sm += __shfl_xor(sm, 32, 64);
            mxv = fmaxf(mxv, __shfl_xor(mxv, 16, 64));
            mxv = fmaxf(mxv, __shfl_xor(mxv, 32, 64));
            if (lane < 16) {
                atomicAdd(&psum[bidx * 1024 + col], sm);
                unsigned tb = __float_as_uint(mxv);
                tb = (tb & 0x80000000u) ? ~tb : (tb | 0x80000000u);
                atomicMax(&pmaxu[bidx * 1024 + col], tb);
            }
        }
    } else {
        float sx[MR][4] = {};
        #pragma unroll
        for (int mi = 0; mi < MR; mi++) {
            #pragma unroll
            for (int ni = 0; ni < NR; ni++) {
                #pragma unroll
                for (int r = 0; r < 4; r++) {
                    const int row = rb + wr + mi * 16 + cr + r;
                    const int col = cb + wc + ni * 16 + cc;
                    if (col < NC) {
                        float v = acc[mi][ni][r] + (bias ? bias[col] : 0.f);
                        if (col < scale_cols) v *= qs;
                        if (resid) v += resid[(size_t)row * NC + col];
                        if (gamma) {
                            v = v * (gamma[col] * BN_SCALE) + beta[col];
                            v = v >= 0.f ? v : 0.2f * v;
                        }
                        if (yco > 0) {
                            if (col < yco) Cout[(size_t)row * yco + col] = v;
                            else           Cz[(size_t)row * yco + (col - yco)] = v;
                        } else {
                            Cout[(size_t)row * NC + col] = v;
                        }
                        if (obf) obf[(size_t)row * NC + col] = F2BF(v);
                        if constexpr (SPLIT > 0) {
                            constexpr int KP2 = 3 * SPLIT;
                            const unsigned short h = F2BF(v);
                            const unsigned short l = F2BF(v - US2F(h));
                            sxa[(size_t)row * KP2 + 0 * SPLIT + col] = h;
                            sxa[(size_t)row * KP2 + 1 * SPLIT + col] = l;
                            sxa[(size_t)row * KP2 + 2 * SPLIT + col] = h;
                            sxb[(size_t)row * KP2 + 0 * SPLIT + col] = h;
                            sxb[(size_t)row * KP2 + 1 * SPLIT + col] = h;
                            sxb[(size_t)row * KP2 + 2 * SPLIT + col] = l;
                            sx[mi][r] += v * v;
                        }
                    }
                }
            }
        }
        if constexpr (SPLIT > 0) {
            #pragma unroll
            for (int mi = 0; mi < MR; mi++) {
                #pragma unroll
                for (int r = 0; r < 4; r++) {
                    float s = sx[mi][r];
                    s += __shfl_xor(s, 1, 64);
                    s += __shfl_xor(s, 2, 64);
                    s += __shfl_xor(s, 4, 64);
                    s += __shfl_xor(s, 8, 64);
                    if ((lane & 15) == 0)
                        atomicAdd(&xxo[rb + wr + mi * 16 + cr + r], s);
                }
            }
        }
    }
}

// AFF: remap blockIdx.x so row-block batch == XCD (linear id % 8).
template<int KD, int NC, int TM, int TN, bool CATA = false, bool POOL = false, int SPLIT = 0, bool AFF = false>
__global__ __launch_bounds__(256) void k_gemmb(const unsigned short* __restrict__ A,
                                               const unsigned short* __restrict__ A2,
                                               const unsigned short* __restrict__ A3,
                                               const unsigned short* __restrict__ A4,
                                               const unsigned short* __restrict__ Bw,
                                               const float* __restrict__ bias,
                                               const float* __restrict__ resid,
                                               float* __restrict__ Cout,
                                               int scale_cols, float qs,
                                               const float* __restrict__ gamma,
                                               const float* __restrict__ beta,
                                               unsigned short* __restrict__ obf,
                                               unsigned* __restrict__ pmaxu,
                                               float* __restrict__ psum,
                                               unsigned short* __restrict__ sxa,
                                               unsigned short* __restrict__ sxb,
                                               float* __restrict__ xxo) {
    int bx = blockIdx.x;
    if constexpr (AFF) bx = (bx & 7) * (gridDim.x >> 3) + (bx >> 3);
    gemm_dev<KD, NC, TM, TN, CATA, POOL, SPLIT>(bx, blockIdx.y,
        A, A2, A3, A4, Bw, bias, resid, Cout, nullptr, 0, scale_cols, qs, gamma, beta,
        obf, pmaxu, psum, sxa, sxb, xxo);
}

// ---------------------------------------------------------------- combined pdm || yz-GEMM (+aux prep)
// blocks [0,512) = pdm (batch-affine), [512,auxbase) = yz gemm (batch-affine
// remap), [auxbase,..) = deferred weight-conversion / transpose work (layer-1
// launch only) filling CU tail-time.
template<int KP, int KDY, int NCY, int TMY, int TNY>
__global__ __launch_bounds__(256) void k_pdmyz(const unsigned short* __restrict__ xa,
                                               const unsigned short* __restrict__ xb,
                                               const float* __restrict__ xx,
                                               float* __restrict__ pd,
                                               const unsigned short* __restrict__ Ay,
                                               const unsigned short* __restrict__ Bwy,
                                               float* __restrict__ Cy,
                                               float* __restrict__ Cz, int yco, int gxy,
                                               int auxbase, TList tlb, int nlb, int nbb,
                                               TrP trp, int ntr, DetP dp) {
    if ((int)blockIdx.x >= auxbase) {       // ---- aux prep region
        int ab = blockIdx.x - auxbase;
        const int isbf = det_isbf(dp);
        if (ab < nbb) { prep_entry(tlb, nlb, ab, isbf); return; }
        ab -= nbb;
        if (ab < ntr) tr_entry(trp, ab, isbf);
        return;
    }
    if ((int)blockIdx.x < 512) { pdm_dev<KP, 128, 128>(blockIdx.x, xa, xb, xx, pd); return; }
    const int g = blockIdx.x - 512;           // 512 ≡ 0 mod 8 -> XCD = g&7
    const int batch = g & 7, rem = g >> 3;
    const int rpb = gxy >> 3;                 // row-blocks per batch
    const int bx = batch * rpb + rem % rpb;
    const int by = rem / rpb;
    gemm_dev<KDY, NCY, TMY, TNY, false, false, 0>(bx, by,
        Ay, nullptr, nullptr, nullptr, Bwy, nullptr, nullptr, Cy, Cz, yco, 0, 1.f,
        nullptr, nullptr, nullptr, nullptr, nullptr, nullptr, nullptr, nullptr);
}

// ---------------------------------------------------------------- fused top-20 selection + EdgeConv gather (+aux)
// 2048 blocks (32 waves/CU TLP for the serial 20-round chain -- R5/R6 lesson);
// wave w selects row i0+w's top-20 from pd (local XCD L2), indices go through
// LDS, then the block gathers y-rows for its 4 points (batch-affine) and
// applies the epilogue.  Blocks >=2048: deferred prep work (layer-1 only).
template<int CO>
__global__ __launch_bounds__(256) void k_seledge(const float* __restrict__ pd,
                                                 const float* __restrict__ y,
                                                 const float* __restrict__ z,
                                                 const float* __restrict__ g,
                                                 const float* __restrict__ bb,
                                                 float* __restrict__ out,
                                                 unsigned short* __restrict__ outb,
                                                 TList tlc, int nlc, DetP dp) {
    const int t = threadIdx.x;
    const int blk = blockIdx.x;
    if (blk >= 2048) {                      // ---- aux prep region
        prep_entry(tlc, nlc, blk - 2048, det_isbf(dp));
        return;
    }
    const int w = t >> 6, lane = t & 63;
    const int b = blk & 7;
    const int i0 = (b << 10) + ((blk >> 3) << 2);      // 4 rows per block
    const int bbase = b << 10;
    __shared__ int sidx[4][K_];
    {   // ---- selection (verbatim sel_dev logic, row = i0 + w)
        const int i = i0 + w;
        const float* row = pd + (size_t)b * N_ * N_ + (size_t)(i & 1023) * N_;
        unsigned key[16];
        #pragma unroll
        for (int q = 0; q < 16; q++) {
            const int j = q * 64 + lane;
            unsigned bits = __float_as_uint(row[j]);
            bits = (bits & 0x80000000u) ? ~bits : (bits | 0x80000000u);
            key[q] = (bits & 0xFFFFFC00u) | (unsigned)(N_ - 1 - j);
        }
        int myj = 0;
        for (int kk = 0; kk < K_; kk++) {
            unsigned m = key[0];
            #pragma unroll
            for (int u = 1; u < 16; u++) m = key[u] > m ? key[u] : m;
            #pragma unroll
            for (int s = 1; s < 64; s <<= 1) {
                unsigned o = (unsigned)__shfl_xor((int)m, s, 64);
                m = o > m ? o : m;
            }
            const int j = N_ - 1 - (int)(m & 1023u);
            if (lane == kk) myj = j;
            #pragma unroll
            for (int u = 0; u < 16; u++)
                if (key[u] == m) key[u] = 0u;      // below any plausible real key
        }
        if (lane < K_) sidx[w][lane] = myj;
    }
    __syncthreads();
    // ---- gather + epilogue (4 points x CO/4 float4 cols)
    constexpr int TPP = CO / 4;
    if (t < 4 * TPP) {
        const int p = t / TPP;
        const int cw = (t % TPP) * 4;
        const int ig = i0 + p;
        float4 m = {-3e38f, -3e38f, -3e38f, -3e38f};
        #pragma unroll 4
        for (int k = 0; k < K_; k++) {
            const int jg = bbase + sidx[p][k];
            const float4 yv = *reinterpret_cast<const float4*>(&y[(size_t)jg * CO + cw]);
            m.x = fmaxf(m.x, yv.x); m.y = fmaxf(m.y, yv.y);
            m.z = fmaxf(m.z, yv.z); m.w = fmaxf(m.w, yv.w);
        }
        const float4 yi = *reinterpret_cast<const float4*>(&y[(size_t)ig * CO + cw]);
        const float4 zi = *reinterpret_cast<const float4*>(&z[(size_t)ig * CO + cw]);
        const float4 gv = *reinterpret_cast<const float4*>(&g[cw]);
        const float4 bv = *reinterpret_cast<const float4*>(&bb[cw]);
        float vals[4] = {m.x - yi.x + zi.x, m.y - yi.y + zi.y,
                         m.z - yi.z + zi.z, m.w - yi.w + zi.w};
        float gs[4] = {gv.x, gv.y, gv.z, gv.w};
        float bs[4] = {bv.x, bv.y, bv.z, bv.w};
        float4 o;
        float* op = &o.x;
        #pragma unroll
        for (int j = 0; j < 4; j++) {
            float h = vals[j] * (gs[j] * BN_SCALE) + bs[j];
            op[j] = h >= 0.f ? h : 0.2f * h;
        }
        *reinterpret_cast<float4*>(&out[(size_t)ig * CO + cw]) = o;
        #pragma unroll
        for (int j = 0; j < 4; j++) outb[(size_t)ig * CO + cw + j] = F2BF(op[j]);
    }
}

// ---------------------------------------------------------------- attention (layer 4 only)
// R13 lesson: scalar E=256 out-proj fusion ran at 85us (VALU-bound, LDS chunk
// reloads).  Scalar out-proj only beats MFMA+boundary when wo fits LDS whole
// (E<=128): layer 4 keeps attn -> owb -> MFMA gemm.
template<int E>
__global__ __launch_bounds__(256) void k_attn(const float* __restrict__ qkv,
                                              unsigned short* __restrict__ o) {
    constexpr int H = 4, D = E / H, L = 8;
    const int n = blockIdx.x;
    const int t = threadIdx.x;
    const int h = t >> 6, lane = t & 63;
    __shared__ float sq[L][3 * E];
    __shared__ float so[L][E];
    for (int u = t; u < L * 3 * E; u += 256) {
        int l = u / (3 * E), r = u - l * (3 * E);
        sq[l][r] = qkv[(size_t)(l * N_ + n) * (3 * E) + r];
    }
    __syncthreads();
    const int l = lane >> 3, m = lane & 7;
    float s = 0.f;
    #pragma unroll 8
    for (int dd = 0; dd < D; dd++)
        s += sq[l][h * D + dd] * sq[m][E + h * D + dd];
    float mx = s;
    #pragma unroll
    for (int st = 1; st < 8; st <<= 1) mx = fmaxf(mx, __shfl_xor(mx, st, 64));
    float e = expf(s - mx);
    float sum = e;
    #pragma unroll
    for (int st = 1; st < 8; st <<= 1) sum += __shfl_xor(sum, st, 64);
    const float p = e / sum;
    float pm[8];
    #pragma unroll
    for (int mm = 0; mm < 8; mm++) pm[mm] = __shfl(p, (lane & 56) | mm, 64);
    #pragma unroll
    for (int j = 0; j < D / 8; j++) {
        const int dd = m + 8 * j;
        float a = 0.f;
        #pragma unroll
        for (int mm = 0; mm < 8; mm++) a += pm[mm] * sq[mm][2 * E + h * D + dd];
        so[l][h * D + dd] = a;
    }
    __syncthreads();
    for (int u = t; u < L * E; u += 256) {
        int l2 = u / E, e2 = u - l2 * E;
        o[(size_t)(l2 * N_ + n) * E + e2] = F2BF(so[l2][e2]);
    }
}

// ---------------------------------------------------------------- fused attention + out-proj (layers 1-3)
template<int E, int SPLIT>
__global__ __launch_bounds__(256) void k_attnout(const float* __restrict__ qkv,
                                                 const unsigned short* __restrict__ wo,
                                                 const float* __restrict__ bo,
                                                 float* __restrict__ x,
                                                 unsigned short* __restrict__ xob,
                                                 unsigned short* __restrict__ sxa,
                                                 unsigned short* __restrict__ sxb,
                                                 float* __restrict__ xxo) {
    constexpr int H = 4, D = E / H, L = 8;
    const int n = blockIdx.x;
    const int t = threadIdx.x;
    const int h = t >> 6, lane = t & 63;
    __shared__ float sq[L][3 * E];
    __shared__ float so[L][E];
    __shared__ unsigned short swo[E][E + 8];
    __shared__ float sxx[L];
    for (int u = t; u < L * 3 * E; u += 256) {
        int l = u / (3 * E), r = u - l * (3 * E);
        sq[l][r] = qkv[(size_t)(l * N_ + n) * (3 * E) + r];
    }
    for (int u = t; u < E * E; u += 256) swo[u / E][u % E] = wo[u];
    if (t < L) sxx[t] = 0.f;
    __syncthreads();
    const int l = lane >> 3, m = lane & 7;
    float s = 0.f;
    #pragma unroll 8
    for (int dd = 0; dd < D; dd++)
        s += sq[l][h * D + dd] * sq[m][E + h * D + dd];
    float mx = s;
    #pragma unroll
    for (int st = 1; st < 8; st <<= 1) mx = fmaxf(mx, __shfl_xor(mx, st, 64));
    float e = expf(s - mx);
    float sum = e;
    #pragma unroll
    for (int st = 1; st < 8; st <<= 1) sum += __shfl_xor(sum, st, 64);
    const float p = e / sum;
    float pm[8];
    #pragma unroll
    for (int mm = 0; mm < 8; mm++) pm[mm] = __shfl(p, (lane & 56) | mm, 64);
    #pragma unroll
    for (int j = 0; j < D / 8; j++) {
        const int dd = m + 8 * j;
        float a = 0.f;
        #pragma unroll
        for (int mm = 0; mm < 8; mm++) a += pm[mm] * sq[mm][2 * E + h * D + dd];
        so[l][h * D + dd] = a;
    }
    __syncthreads();
    for (int u = t; u < L * E; u += 256)
        so[u / E][u % E] = US2F(F2BF(so[u / E][u % E]));
    __syncthreads();
    constexpr int PT = (L * E) / 256;
    #pragma unroll
    for (int it = 0; it < PT; it++) {
        const int item = t + it * 256;
        const int ll = item / E, ee = item % E;
        float acc = 0.f;
        #pragma unroll 16
        for (int c = 0; c < E; c++)
            acc += so[ll][c] * US2F(swo[ee][c]);
        const int row = ll * N_ + n;
        const float v = acc + bo[ee] + x[(size_t)row * E + ee];
        x[(size_t)row * E + ee] = v;
        xob[(size_t)row * E + ee] = F2BF(v);
        if constexpr (SPLIT > 0) {
            constexpr int KP2 = 3 * SPLIT;
            const unsigned short hh = F2BF(v);
            const unsigned short lo = F2BF(v - US2F(hh));
            sxa[(size_t)row * KP2 + 0 * SPLIT + ee] = hh;
            sxa[(size_t)row * KP2 + 1 * SPLIT + ee] = lo;
            sxa[(size_t)row * KP2 + 2 * SPLIT + ee] = hh;
            sxb[(size_t)row * KP2 + 0 * SPLIT + ee] = hh;
            sxb[(size_t)row * KP2 + 1 * SPLIT + ee] = hh;
            sxb[(size_t)row * KP2 + 2 * SPLIT + ee] = lo;
            float vs = v * v;
            #pragma unroll
            for (int st = 1; st < 64; st <<= 1) vs += __shfl_xor(vs, st, 64);
            if (lane == 0) atomicAdd(&sxx[ll], vs);
        }
    }
    if constexpr (SPLIT > 0) {
        __syncthreads();
        if (t < L) xxo[t * N_ + n] = sxx[t];
    }
}

// ---------------------------------------------------------------- FC head
__global__ __launch_bounds__(256) void k_fc1(const unsigned* __restrict__ pmaxu,
                                             const float* __restrict__ psum,
                                             const float* __restrict__ l1wT,
                                             const float* __restrict__ g6, const float* __restrict__ b6,
                                             float* __restrict__ f1) {
    int oc = blockIdx.x, b = blockIdx.y, t = threadIdx.x;
    __shared__ float fin[2048];
    __shared__ float ps[4][64];
    for (int u = t; u < 2048; u += 256) {
        float v;
        if (u < 1024) {
            unsigned tb = pmaxu[b * 1024 + u];
            unsigned bits = (tb & 0x80000000u) ? (tb & 0x7FFFFFFFu) : ~tb;
            v = __uint_as_float(bits);
        } else {
            v = psum[b * 1024 + (u - 1024)] * (1.f / 1024.f);
        }
        fin[u] = v;
    }
    __syncthreads();
    int ol = t & 63, kc = t >> 6;
    int o = oc * 64 + ol;
    float acc = 0.f;
    for (int c = kc * 512; c < kc * 512 + 512; c++) acc += fin[c] * l1wT[(size_t)c * 512 + o];
    ps[kc][ol] = acc;
    __syncthreads();
    if (t < 64) {
        int oo = oc * 64 + t;
        float a = ps[0][t] + ps[1][t] + ps[2][t] + ps[3][t];
        float h = a * (g6[oo] * BN_SCALE) + b6[oo];
        f1[b * 512 + oo] = h >= 0.f ? h : 0.2f * h;
    }
}

__global__ __launch_bounds__(256) void k_fc23(const float* __restrict__ f1, const float* __restrict__ l2wT,
                                              const float* __restrict__ l2b,
                                              const float* __restrict__ g7, const float* __restrict__ b7,
                                              const float* __restrict__ l3wT, const float* __restrict__ l3b,
                                              void* __restrict__ out, DetP dp) {
    int b = blockIdx.x, t = threadIdx.x;
    __shared__ float fin[512];
    __shared__ float f2s[256];
    __shared__ int sbf;
    if (t == 0) sbf = det_isbf(dp);
    for (int u = t; u < 512; u += 256) fin[u] = f1[b * 512 + u];
    __syncthreads();
    {
        float acc = 0.f;
        for (int c = 0; c < 512; c++) acc += fin[c] * l2wT[(size_t)c * 256 + t];
        acc += l2b[t];
        float h = acc * (g7[t] * BN_SCALE) + b7[t];
        f2s[t] = h >= 0.f ? h : 0.2f * h;
    }
    __syncthreads();
    if (t < 40) {
        float acc = 0.f;
        for (int c = 0; c < 256; c++) acc += f2s[c] * l3wT[(size_t)c * 40 + t];
        acc += l3b[t];
        if (sbf) ((__hip_bfloat16*)out)[b * 40 + t] = __float2bfloat16(acc);
        else     ((float*)out)[b * 40 + t] = acc;
    }
}

// ================================================================ host
extern "C" void kernel_launch(void* const* d_in, const int* in_sizes, int n_in,
                              void* d_out, int out_size, void* d_ws, size_t ws_size,
                              hipStream_t stream) {
    auto us = [&](int i) { return (const unsigned short*)d_in[i]; };

    float* ws = (float*)d_ws;
    size_t off = 0;
    auto A = [&](size_t n) { float* p = ws + off; off += (n + 3) & ~(size_t)3; return p; };
    auto AU = [&](size_t n) { return (unsigned short*)A((n + 1) / 2); };
    float* x1   = A((size_t)BN_ * 64);
    float* x2   = A((size_t)BN_ * 64);
    float* x3   = A((size_t)BN_ * 128);
    float* x4   = A((size_t)BN_ * 256);
    float* pd   = A((size_t)BN_ * 1024);   // pd scratch
    float* f1   = A(8 * 512);
    float* xx   = A(4 * BN_);              // per-layer row norms
    float* qkvw = A((size_t)BN_ * 768);    // qkv / y,z scratch
    // dedicated kNN split buffers (k_attnout reads qkvw while writing these)
    unsigned short* xa = AU((size_t)BN_ * 384);
    unsigned short* xb = AU((size_t)BN_ * 384);
    // bf16 activation copies
    unsigned short* xf0b = AU((size_t)BN_ * 3);
    unsigned short* x1b  = AU((size_t)BN_ * 64);
    unsigned short* x2b  = AU((size_t)BN_ * 64);
    unsigned short* x3b  = AU((size_t)BN_ * 128);
    unsigned short* x4b  = AU((size_t)BN_ * 256);
    unsigned short* owb  = AU((size_t)BN_ * 256);   // layer-4 attn output
    // pooled reductions (conv5 fused epilogue) -- contiguous, zeroed by k_prep
    unsigned* pmaxu = (unsigned*)A(8 * 1024);
    float*    psum  = A(8 * 1024);
    // bf16 weights (n,k) layouts
    unsigned short* w1yzb = AU(128 * 3);
    unsigned short* w2yzb = AU(128 * 64);
    unsigned short* w3yzb = AU(256 * 64);
    unsigned short* w4yzb = AU(512 * 128);
    unsigned short* a1wib = AU(192 * 64);  unsigned short* a1wob = AU(64 * 64);
    unsigned short* a2wib = AU(192 * 64);  unsigned short* a2wob = AU(64 * 64);
    unsigned short* a3wib = AU(384 * 128); unsigned short* a3wob = AU(128 * 128);
    unsigned short* a4wib = AU(768 * 256); unsigned short* a4wob = AU(256 * 256);
    unsigned short* w5b   = AU(1024 * 512);
    // fp32 fc weights (transposed)
    float* l1wT  = A(2048 * 512);
    float* l2wT  = A(512 * 256);
    float* l3wT  = A(256 * 40);
    // converted vectors (fp32)
    float* g1f = A(64);   float* b1f = A(64);
    float* g2f = A(64);   float* b2f = A(64);
    float* g3f = A(128);  float* b3f = A(128);
    float* g4f = A(256);  float* b4f = A(256);
    float* bi1 = A(192);  float* bo1 = A(64);
    float* bi2 = A(192);  float* bo2 = A(64);
    float* bi3 = A(384);  float* bo3 = A(128);
    float* bi4 = A(768);  float* bo4 = A(256);
    float* g5f = A(1024); float* b5f = A(1024);
    float* g6f = A(512);  float* b6f = A(512);
    float* l2bf = A(256);
    float* g7f = A(256);  float* b7f = A(256);
    float* l3bf = A(40);

    float* xx1 = xx;              float* xx2 = xx + BN_;
    float* xx3 = xx + 2 * BN_;    float* xx4 = xx + 3 * BN_;

    // y/z edge-feature arrays alias qkvw (qkv gemm later overwrites)
    float* yy = qkvw;
    float* zz = qkvw + (size_t)BN_ * 256;

    DetP dp{{us(2), us(5), us(8), us(11), us(30), us(33), us(37)}};

    // ---- list A: critical prep (consumed by layer-1 launches / small vectors)
    TList tlA; int nbA = 0, kA = 0;
    auto addA = [&](int i, void* dst, int O, int I, int mode) {
        tlA.p[kA] = {d_in[i], dst, O, I, nbA, mode};
        nbA += (O * I + 255) / 256; kA++;
    };
    addA(0,  xf0b,  BN_ * 3, 1, 2);
    addA(0,  pmaxu, 16384, 1, 4);      // zero pmaxu+psum (contiguous)
    addA(1,  w1yzb, 64, 6, 3);
    addA(13, a1wib, 192, 64, 2);
    addA(15, a1wob, 64, 64, 2);
    addA(2,  g1f, 64, 1, 0);   addA(3,  b1f, 64, 1, 0);
    addA(5,  g2f, 64, 1, 0);   addA(6,  b2f, 64, 1, 0);
    addA(8,  g3f, 128, 1, 0);  addA(9,  b3f, 128, 1, 0);
    addA(11, g4f, 256, 1, 0);  addA(12, b4f, 256, 1, 0);
    addA(14, bi1, 192, 1, 0);  addA(16, bo1, 64, 1, 0);
    addA(18, bi2, 192, 1, 0);  addA(20, bo2, 64, 1, 0);
    addA(22, bi3, 384, 1, 0);  addA(24, bo3, 128, 1, 0);
    addA(26, bi4, 768, 1, 0);  addA(28, bo4, 256, 1, 0);
    addA(30, g5f, 1024, 1, 0); addA(31, b5f, 1024, 1, 0);
    addA(33, g6f, 512, 1, 0);  addA(34, b6f, 512, 1, 0);
    addA(36, l2bf, 256, 1, 0);
    addA(37, g7f, 256, 1, 0);  addA(38, b7f, 256, 1, 0);
    addA(40, l3bf, 40, 1, 0);

    // ---- list B: deferred into layer-1 pdmyz (consumers >= layer-2 pdmyz)
    TList tlB; int nbB = 0, kB = 0;
    auto addB = [&](int i, void* dst, int O, int I, int mode) {
        tlB.p[kB] = {d_in[i], dst, O, I, nbB, mode};
        nbB += (O * I + 255) / 256; kB++;
    };
    addB(4,  w2yzb, 64, 128, 3);
    addB(7,  w3yzb, 128, 128, 3);
    addB(10, w4yzb, 256, 256, 3);
    addB(17, a2wib, 192, 64, 2);
    addB(19, a2wob, 64, 64, 2);
    addB(21, a3wib, 384, 128, 2);
    addB(23, a3wob, 128, 128, 2);

    // ---- list C: deferred into layer-1 seledge (consumers >= layer-4 qkv)
    TList tlC; int nbC = 0, kC = 0;
    auto addC = [&](int i, void* dst, int O, int I, int mode) {
        tlC.p[kC] = {d_in[i], dst, O, I, nbC, mode};
        nbC += (O * I + 255) / 256; kC++;
    };
    addC(25, a4wib, 768, 256, 2);
    addC(27, a4wob, 256, 256, 2);
    addC(29, w5b,   1024, 512, 2);

    // transposes: l2wT/l3wT stay in prep (small); l1wT (1024 blocks) deferred.
    TrP tp2{d_in[35], l2wT, 256, 512,  512 / 32,  0};
    TrP tp3{d_in[39], l3wT, 40,  256,  256 / 32,  (512 / 32) * (256 / 32)};
    const int trprep = tp3.blk0 + (256 / 32) * ((40 + 31) / 32);   // 128 + 16
    TrP tp1{d_in[32], l1wT, 512, 2048, 2048 / 32, 0};
    const int tr1blocks = (2048 / 32) * (512 / 32);                // 1024

    const int splblocks = (BN_ * 32) / 256 + 32;   // L1 split + norms
    k_prep<<<nbA + trprep + splblocks, 256, 0, stream>>>(
        tlA, kA, tp2, tp3, nbA, trprep, d_in[0], dp, xa, xb, xx1);

    const unsigned short* N0 = nullptr;
    unsigned short* U0 = nullptr;
    unsigned* NU = nullptr; float* NF = nullptr;

    // layer 1  (C=3 -> 64) -- pdmyz carries list-B + l1wT-transpose aux blocks
    k_pdmyz<32, 3, 128, 64, 64><<<768 + nbB + tr1blocks, 256, 0, stream>>>(
        xa, xb, xx1, pd, xf0b, w1yzb, yy, zz, 64, 128,
        768, tlB, kB, nbB, tp1, tr1blocks, dp);
    k_seledge<64><<<2048 + nbC, 256, 0, stream>>>(pd, yy, zz, g1f, b1f, x1, x1b, tlC, kC, dp);
    k_gemmb<64, 192, 64, 64, false, false, 0, true><<<dim3(128, 3), 256, 0, stream>>>(x1b, N0, N0, N0, a1wib, bi1, nullptr, qkvw, 64, 0.25f, nullptr, nullptr, nullptr, NU, NF, U0, U0, NF);
    k_attnout<64, 64><<<N_, 256, 0, stream>>>(qkvw, a1wob, bo1, x1, x1b, xa, xb, xx2);

    // layer 2  (C=64 -> 64, KP=192)
    k_pdmyz<192, 64, 128, 64, 64><<<768, 256, 0, stream>>>(
        xa, xb, xx2, pd, x1b, w2yzb, yy, zz, 64, 128,
        768, tlB, 0, 0, tp1, 0, dp);
    k_seledge<64><<<2048, 256, 0, stream>>>(pd, yy, zz, g2f, b2f, x2, x2b, tlC, 0, dp);
    k_gemmb<64, 192, 64, 64, false, false, 0, true><<<dim3(128, 3), 256, 0, stream>>>(x2b, N0, N0, N0, a2wib, bi2, nullptr, qkvw, 64, 0.25f, nullptr, nullptr, nullptr, NU, NF, U0, U0, NF);
    k_attnout<64, 64><<<N_, 256, 0, stream>>>(qkvw, a2wob, bo2, x2, x2b, xa, xb, xx3);

    // layer 3  (C=64 -> 128, KP=192)
    k_pdmyz<192, 64, 256, 64, 64><<<1024, 256, 0, stream>>>(
        xa, xb, xx3, pd, x2b, w3yzb, yy, zz, 128, 128,
        1024, tlB, 0, 0, tp1, 0, dp);
    k_seledge<128><<<2048, 256, 0, stream>>>(pd, yy, zz, g3f, b3f, x3, x3b, tlC, 0, dp);
    k_gemmb<128, 384, 64, 128, false, false, 0, true><<<dim3(128, 3), 256, 0, stream>>>(x3b, N0, N0, N0, a3wib, bi3, nullptr, qkvw, 128, 0.17677669529663687f, nullptr, nullptr, nullptr, NU, NF, U0, U0, NF);
    k_attnout<128, 128><<<N_, 256, 0, stream>>>(qkvw, a3wob, bo3, x3, x3b, xa, xb, xx4);

    // layer 4  (C=128 -> 256, KP=384; E=256 keeps attn -> owb -> MFMA out-proj)
    k_pdmyz<384, 128, 512, 128, 128><<<768, 256, 0, stream>>>(
        xa, xb, xx4, pd, x3b, w4yzb, yy, zz, 256, 64,
        768, tlB, 0, 0, tp1, 0, dp);
    k_seledge<256><<<2048, 256, 0, stream>>>(pd, yy, zz, g4f, b4f, x4, x4b, tlC, 0, dp);
    k_gemmb<256, 768, 64, 128, false, false, 0, true><<<dim3(128, 6), 256, 0, stream>>>(x4b, N0, N0, N0, a4wib, bi4, nullptr, qkvw, 256, 0.125f, nullptr, nullptr, nullptr, NU, NF, U0, U0, NF);
    k_attn<256><<<N_, 256, 0, stream>>>(qkvw, owb);
    k_gemmb<256, 256, 64, 128, false, false, 0, true><<<dim3(128, 2), 256, 0, stream>>>(owb, N0, N0, N0, a4wob, bo4, x4, x4, 0, 1.f, nullptr, nullptr, x4b, NU, NF, U0, U0, NF);

    // head: conv5 with fused concat-A and fused pooling epilogue (batch-affine)
    k_gemmb<512, 1024, 128, 128, true, true, 0, true><<<dim3(64, 8), 256, 0, stream>>>(
        x1b, x2b, x3b, x4b, w5b, nullptr, nullptr, nullptr, 0, 1.f, g5f, b5f, nullptr, pmaxu, psum, U0, U0, NF);
    k_fc1<<<dim3(8, 8), 256, 0, stream>>>(pmaxu, psum, l1wT, g6f, b6f, f1);
    k_fc23<<<8, 256, 0, stream>>>(f1, l2wT, l2bf, g7f, b7f, l3wT, l3bf, d_out, dp);
}